// Round 1
// baseline (169453.589 us; speedup 1.0000x reference)
//
#include <hip/hip_runtime.h>
#include <cstdint>
#include <cstddef>

// ============================================================================
// Aligner (forward attention + GRU), persistent-kernel implementation.
//
// Per scan step j (3 device-wide barrier phases):
//  PA: fused GEMM X[32,1920] x Wcat[1920,4096] -> gates r,z,n(+split x/h) and
//      trans-preact rows; GRU update h_new; per-block trans partials.
//      Also: write alpha_{j-1} to d_out, reset this-parity accumulators.
//  PQ: q = h_new @ w_q^T  (32x512, K=1024); reduce trans partials -> TRED.
//  PB: energy_s = sum_c w_agg_c*tanh(conv(align)_{c,s} + q_c + key_{c,s});
//      e_s = exp(E); alpha_new ~ ((1-t)a + t a_shift + 1e-7)*e  (softmax
//      denominator cancels algebraically); accumulate Sum_e, Sum_w, and
//      prevU_i = sum_s w_s enc[s,i] (= unnormalized attend = next prev).
//      Stage next query/frame slices into k-major layout.
// State double-buffered by parity; PA(j) resets parity-p accumulators that
// PB(j) atomically accumulates and PA/PB(j+1) read.
// ============================================================================

namespace cfg {
constexpr int NB = 32, NS = 256, NI = 512, NHq = 256, NM = 80;
constexpr int NC = 1024, NC2 = 512, NKW = 31, NT = 800;
constexpr int KTOT = 1920;   // padded K: query 256 | prev 512 | h 1024 | frame 80 | pad 48
constexpr int NROW = 4096;   // rows: r | z | n | tp  (1024 each)
constexpr int NBLK = 256, NTHR = 512;

constexpr size_t OFF_WCAT  = 0;                                   // 4096*1920
constexpr size_t OFF_KEYT  = OFF_WCAT + (size_t)NROW * KTOT;      // 32*256*512
constexpr size_t OFF_WCOMB = OFF_KEYT + (size_t)NB * NS * NC2;    // 31*512 (k-major)
constexpr size_t OFF_WKT   = OFF_WCOMB + (size_t)NKW * NC2;       // 512*512
constexpr size_t OFF_XQ    = OFF_WKT + (size_t)NI * NC2;          // 2*256*32
constexpr size_t OFF_XF    = OFF_XQ + (size_t)2 * NHq * NB;       // 2*80*32
constexpr size_t OFF_PREVU = OFF_XF + (size_t)2 * NM * NB;        // 2*512*32
constexpr size_t OFF_H     = OFF_PREVU + (size_t)2 * NI * NB;     // 2*1024*32
constexpr size_t OFF_E     = OFF_H + (size_t)2 * NC * NB;         // 2*32*256
constexpr size_t OFF_W     = OFF_E + (size_t)2 * NB * NS;         // 2*32*256
constexpr size_t OFF_SE    = OFF_W + (size_t)2 * NB * NS;         // 2*32
constexpr size_t OFF_SW    = OFF_SE + (size_t)2 * NB;             // 2*32
constexpr size_t OFF_TPART = OFF_SW + (size_t)2 * NB;             // 256*32
constexpr size_t OFF_TRED  = OFF_TPART + (size_t)NBLK * NB;       // 32
constexpr size_t OFF_QBUF  = OFF_TRED + 32;                       // 32*512
constexpr size_t OFF_BAR   = OFF_QBUF + (size_t)NB * NC2;         // 256 uints
constexpr size_t WS_FLOATS = OFF_BAR + 256;
}
using namespace cfg;

__device__ __forceinline__ float frcp(float x) {
#if __has_builtin(__builtin_amdgcn_rcpf)
  return __builtin_amdgcn_rcpf(x);
#else
  return 1.f / x;
#endif
}
__device__ __forceinline__ float fsig(float x) { return frcp(1.f + __expf(-x)); }
__device__ __forceinline__ float ftanh(float x) {
  const float e = __expf(2.f * x);
  return 1.f - 2.f * frcp(e + 1.f);
}

// Two-level barrier among 256 co-resident blocks (8 groups of 32).
__device__ __forceinline__ void gbarrier(unsigned* bar, int& ph) {
  ++ph;
  __syncthreads();
  if (threadIdx.x == 0) {
    __threadfence();  // release: flush our writes device-wide
    const int g = blockIdx.x >> 5;
    const unsigned old = atomicAdd(&bar[(1 + g) * 16], 1u);
    if (old == 32u * (unsigned)ph - 1u) atomicAdd(&bar[0], 1u);
    const unsigned tgt = 8u * (unsigned)ph;
    while (__hip_atomic_load(&bar[0], __ATOMIC_RELAXED, __HIP_MEMORY_SCOPE_AGENT) < tgt)
      __builtin_amdgcn_s_sleep(2);
  }
  __syncthreads();
  __threadfence();  // acquire: invalidate stale L1/L2 before reading others' data
}

// ---------------------------------------------------------------------------
// K1: build Wcat / wcombT / w_kT and initialize all state (runs every call;
// ws is re-poisoned by the harness before each timed launch).
// ---------------------------------------------------------------------------
__global__ void k_init(const float* __restrict__ enc, const float* __restrict__ queries,
                       const float* __restrict__ w_ih, const float* __restrict__ w_hh,
                       const float* __restrict__ w_t1, const float* __restrict__ w_loc1,
                       const float* __restrict__ w_loc2, const float* __restrict__ w_k,
                       float* __restrict__ ws) {
  const size_t t0 = (size_t)blockIdx.x * blockDim.x + threadIdx.x;
  const size_t gs = (size_t)gridDim.x * blockDim.x;
  // Wcat[j][k]; rows j: kind=j>>10 in {r,z,n,tp}, c=j&1023.
  for (size_t x = t0; x < (size_t)NROW * KTOT; x += gs) {
    const int k = (int)(x % KTOT), j = (int)(x / KTOT);
    const int c = j & (NC - 1), kind = j >> 10;
    float v = 0.f;
    if (kind < 3) {
      const int gr = kind * NC + c;
      if (k < 768) v = w_ih[(size_t)gr * 768 + k];                 // [query|prev] part
      else if (k < 1792) v = w_hh[(size_t)gr * NC + (k - 768)];    // h part
    } else {  // trans-net row: t_in = [attend(512) | frame(80) | h(1024)]
      if (k >= 256 && k < 768) v = w_t1[(size_t)c * 1616 + (k - 256)];
      else if (k >= 768 && k < 1792) v = w_t1[(size_t)c * 1616 + 592 + (k - 768)];
      else if (k >= 1792 && k < 1872) v = w_t1[(size_t)c * 1616 + 512 + (k - 1792)];
    }
    ws[OFF_WCAT + x] = v;
  }
  // wcombT[k][c2] = sum_l w_loc2[c2,l] * w_loc1[l,0,k]  (fused location conv)
  for (size_t x = t0; x < (size_t)NKW * NC2; x += gs) {
    const int k = (int)(x / NC2), c2 = (int)(x % NC2);
    float s = 0.f;
    for (int l = 0; l < 32; ++l) s += w_loc2[c2 * 32 + l] * w_loc1[l * NKW + k];
    ws[OFF_WCOMB + x] = s;
  }
  // w_kT[i][c2]
  for (size_t x = t0; x < (size_t)NI * NC2; x += gs) {
    const int i = (int)(x / NC2), c2 = (int)(x % NC2);
    ws[OFF_WKT + x] = w_k[(size_t)c2 * NI + i];
  }
  // Xq parity1 = queries[:,0,:] (k-major, b-minor); parity0 = 0
  for (size_t x = t0; x < (size_t)NHq * NB; x += gs) {
    const int k = (int)(x >> 5), b = (int)(x & 31);
    ws[OFF_XQ + x] = 0.f;
    ws[OFF_XQ + (size_t)NHq * NB + x] = queries[(size_t)b * NT * NHq + k];
  }
  for (size_t x = t0; x < (size_t)2 * NM * NB; x += gs) ws[OFF_XF + x] = 0.f;
  // prevU parity1 = enc[b,0,:] (alpha_init is one-hot at s=0, SW=1)
  for (size_t x = t0; x < (size_t)NI * NB; x += gs) {
    const int i = (int)(x >> 5), b = (int)(x & 31);
    ws[OFF_PREVU + x] = 0.f;
    ws[OFF_PREVU + (size_t)NI * NB + x] = enc[(size_t)b * NS * NI + i];
  }
  for (size_t x = t0; x < (size_t)2 * NC * NB; x += gs) ws[OFF_H + x] = 0.f;
  // e parity1 = 1, SE=256 -> align_init = 1/256 ; w parity1 = onehot, SW=1
  for (size_t x = t0; x < (size_t)NB * NS; x += gs) {
    ws[OFF_E + x] = 0.f;
    ws[OFF_E + (size_t)NB * NS + x] = 1.f;
    ws[OFF_W + x] = 0.f;
    ws[OFF_W + (size_t)NB * NS + x] = ((x & (NS - 1)) == 0) ? 1.f : 0.f;
  }
  for (size_t x = t0; x < (size_t)NB; x += gs) {
    ws[OFF_SE + x] = 0.f; ws[OFF_SE + NB + x] = (float)NS;
    ws[OFF_SW + x] = 0.f; ws[OFF_SW + NB + x] = 1.f;
    ws[OFF_TRED + x] = 0.f;
  }
  for (size_t x = t0; x < (size_t)NBLK * NB; x += gs) ws[OFF_TPART + x] = 0.f;
  unsigned* bar = (unsigned*)(ws + OFF_BAR);
  for (size_t x = t0; x < 256; x += gs) bar[x] = 0u;
}

// ---------------------------------------------------------------------------
// K2: keyT[b][s][c2] = enc[b,s,:] @ w_k^T + b_k   (s-major so PB lanes over c2
// are coalesced). One block per (b, 32-s chunk); 4-row enc tiles in LDS.
// ---------------------------------------------------------------------------
__global__ __launch_bounds__(NTHR) void k_key(const float* __restrict__ enc,
                                              const float* __restrict__ b_k,
                                              float* __restrict__ ws) {
  __shared__ float encl[4 * NI];
  const int bid = blockIdx.x, tid = threadIdx.x;
  const int b = bid >> 3, s0 = (bid & 7) * 32;
  const float* wkT = ws + OFF_WKT;
  float* keyT = ws + OFF_KEYT;
  const float bk = b_k[tid];
  for (int q = 0; q < 8; ++q) {
    const int sb = s0 + q * 4;
    for (int x = tid; x < 4 * NI; x += NTHR) {
      const int ss = x >> 9, i = x & (NI - 1);
      encl[x] = enc[((size_t)(b * NS + sb + ss)) * NI + i];
    }
    __syncthreads();
    float a0 = bk, a1 = bk, a2 = bk, a3 = bk;
    for (int i = 0; i < NI; ++i) {
      const float wv = wkT[(size_t)i * NC2 + tid];
      a0 += wv * encl[i];           a1 += wv * encl[NI + i];
      a2 += wv * encl[2 * NI + i];  a3 += wv * encl[3 * NI + i];
    }
    keyT[((size_t)(b * NS + sb + 0)) * NC2 + tid] = a0;
    keyT[((size_t)(b * NS + sb + 1)) * NC2 + tid] = a1;
    keyT[((size_t)(b * NS + sb + 2)) * NC2 + tid] = a2;
    keyT[((size_t)(b * NS + sb + 3)) * NC2 + tid] = a3;
    __syncthreads();
  }
}

// ---------------------------------------------------------------------------
// Main persistent kernel. 256 blocks x 512 threads, co-resident by construction
// (LDS ~42KB, VGPR<=256 enforced by launch bounds -> >=1 block/CU).
// ---------------------------------------------------------------------------
__global__ __launch_bounds__(NTHR, 1) void k_main(
    const float* __restrict__ enc, const float* __restrict__ queries,
    const float* __restrict__ outputs, const float* __restrict__ mask,
    const float* __restrict__ b_ih, const float* __restrict__ b_hh,
    const float* __restrict__ w_q, const float* __restrict__ w_agg,
    const float* __restrict__ b_t1, const float* __restrict__ w_t2,
    float* ws, float* __restrict__ out) {
  const int bid = blockIdx.x, tid = threadIdx.x;
  float* const Wcat = ws + OFF_WCAT;
  float* const keyT = ws + OFF_KEYT;
  float* const wcomb = ws + OFF_WCOMB;
  float* const XQ = ws + OFF_XQ;
  float* const XF = ws + OFF_XF;
  float* const PU = ws + OFF_PREVU;
  float* const HB = ws + OFF_H;
  float* const EB = ws + OFF_E;
  float* const WBUF = ws + OFF_W;
  float* const SEB = ws + OFF_SE;
  float* const SWB = ws + OFF_SW;
  float* const TPART = ws + OFF_TPART;
  float* const TRED = ws + OFF_TRED;
  float* const QBUF = ws + OFF_QBUF;
  unsigned* const bar = (unsigned*)(ws + OFF_BAR);

  __shared__ float Xl[64 * 36];      // X tile [k][b], stride 36 (conflict-free b128)
  __shared__ float Wl[16 * 66];      // W tile [row16][k], stride 66
  __shared__ float red[8 * 32 * 21]; // k-slice partials (also reused in PQ)
  __shared__ float gout[640];
  __shared__ float swinv_l[32];
  __shared__ float tredl[128];
  __shared__ float qpart[512];
  __shared__ float alignl[64];
  __shared__ float wl2[34];
  __shared__ float Epart[32 * 9];
  __shared__ float wstash[32];

  const int k4 = tid >> 5, c4 = (tid >> 3) & 3, b4 = tid & 7;
  const int cs = bid * 4;  // this block's c-chunk (4 GRU channels)
  int ph = 0;

  for (int j = 0; j < NT; ++j) {
    const int p = j & 1;
    const float* Xq_prev = XQ + (size_t)(1 - p) * NHq * NB;
    const float* Xf_prev = XF + (size_t)(1 - p) * NM * NB;
    const float* pu_prev = PU + (size_t)(1 - p) * NI * NB;
    float* pu_cur = PU + (size_t)p * NI * NB;
    const float* h_prev = HB + (size_t)(1 - p) * NC * NB;
    float* h_cur = HB + (size_t)p * NC * NB;
    const float* e_prev = EB + (size_t)(1 - p) * NB * NS;
    float* e_cur = EB + (size_t)p * NB * NS;
    const float* w_prev = WBUF + (size_t)(1 - p) * NB * NS;
    float* w_cur = WBUF + (size_t)p * NB * NS;
    const float* se_prev = SEB + (size_t)(1 - p) * NB;
    float* se_cur = SEB + (size_t)p * NB;
    const float* sw_prev = SWB + (size_t)(1 - p) * NB;
    float* sw_cur = SWB + (size_t)p * NB;

    // ========================== Phase A ==========================
    if (tid < 64) pu_cur[bid * 64 + tid] = 0.f;  // reset accumulators for PB(j)
    if (bid == 0 && tid < NB) se_cur[tid] = 0.f;
    if (bid == 1 && tid < NB) sw_cur[tid] = 0.f;
    if (tid < NB) swinv_l[tid] = 1.f / sw_prev[tid];
    __syncthreads();

    if (j >= 1 && bid < NB && tid < NS)  // emit alpha_{j-1}
      out[((size_t)bid * NT + (j - 1)) * NS + tid] = w_prev[bid * NS + tid] * swinv_l[bid];

    float ar[4] = {0,0,0,0}, az[4] = {0,0,0,0}, anx[4] = {0,0,0,0},
          anh[4] = {0,0,0,0}, atp[4] = {0,0,0,0};

    for (int kt = 0; kt < 30; ++kt) {
      {  // stage X tile: one float4 (4 batches) per thread; k-major sources
        const int kl = tid >> 3;
        const int b0 = (tid & 7) * 4;
        const int gk = kt * 64 + kl;
        float4 v;
        if (gk < 256) v = *(const float4*)&Xq_prev[gk * 32 + b0];
        else if (gk < 768) {
          v = *(const float4*)&pu_prev[(gk - 256) * 32 + b0];
          v.x *= swinv_l[b0]; v.y *= swinv_l[b0 + 1];
          v.z *= swinv_l[b0 + 2]; v.w *= swinv_l[b0 + 3];
        } else if (gk < 1792) v = *(const float4*)&h_prev[(gk - 768) * 32 + b0];
        else if (gk < 1872) v = *(const float4*)&Xf_prev[(gk - 1792) * 32 + b0];
        else v = make_float4(0.f, 0.f, 0.f, 0.f);
        *(float4*)&Xl[kl * 36 + b0] = v;
      }
      {  // stage W tile: rows {r,z,n,tp} x 4 channels, two floats per thread
        const int r16 = tid >> 5;
        const int kk = (tid * 2) & 63;
        const int kind = r16 >> 2, c4s = r16 & 3;
        const int grow = kind * NC + cs + c4s;
        const float2 wv = *(const float2*)&Wcat[(size_t)grow * KTOT + kt * 64 + kk];
        *(float2*)&Wl[r16 * 66 + kk] = wv;
      }
      __syncthreads();
      auto mac4 = [&](float (&an)[4]) {
        #pragma unroll
        for (int i = 0; i < 4; ++i) {
          const int k = k4 * 4 + i;
          const float4 x = *(const float4*)&Xl[k * 36 + b4 * 4];
          const float wr = Wl[(c4) * 66 + k];
          const float wz = Wl[(4 + c4) * 66 + k];
          const float wn = Wl[(8 + c4) * 66 + k];
          const float wt = Wl[(12 + c4) * 66 + k];
          ar[0] += wr * x.x; ar[1] += wr * x.y; ar[2] += wr * x.z; ar[3] += wr * x.w;
          az[0] += wz * x.x; az[1] += wz * x.y; az[2] += wz * x.z; az[3] += wz * x.w;
          an[0] += wn * x.x; an[1] += wn * x.y; an[2] += wn * x.z; an[3] += wn * x.w;
          atp[0] += wt * x.x; atp[1] += wt * x.y; atp[2] += wt * x.z; atp[3] += wt * x.w;
        }
      };
      // n-row splits into x-part (k<768, tiles 0..11) and h-part (tiles 12..29)
      if (kt < 12) mac4(anx); else mac4(anh);
      __syncthreads();
    }
    {  // reduce k-slices: pair via shfl_xor(32), then 8 partials via LDS
      #pragma unroll
      for (int a = 0; a < 4; ++a) {
        ar[a] += __shfl_xor(ar[a], 32);  az[a] += __shfl_xor(az[a], 32);
        anx[a] += __shfl_xor(anx[a], 32); anh[a] += __shfl_xor(anh[a], 32);
        atp[a] += __shfl_xor(atp[a], 32);
      }
      if ((tid & 32) == 0) {
        const int g = tid >> 6, slot = tid & 31;
        float* dst = &red[(g * 32 + slot) * 21];
        #pragma unroll
        for (int a = 0; a < 4; ++a) {
          dst[a] = ar[a]; dst[4 + a] = az[a]; dst[8 + a] = anx[a];
          dst[12 + a] = anh[a]; dst[16 + a] = atp[a];
        }
      }
    }
    __syncthreads();
    for (int o = tid; o < 640; o += NTHR) {
      const int b = o & 31, rk = o >> 5;
      const int c4o = rk / 5, kind = rk % 5;
      const int sl2 = c4o * 8 + (b >> 2), a = kind * 4 + (b & 3);
      float s = 0.f;
      #pragma unroll
      for (int g2 = 0; g2 < 8; ++g2) s += red[(g2 * 32 + sl2) * 21 + a];
      gout[rk * 32 + b] = s;
    }
    __syncthreads();
    if (tid < 128) {  // GRU update + trans partial for this block's 4 channels
      const int c4o = tid >> 5, b = tid & 31;
      const int c = cs + c4o;
      const float xr = gout[(c4o * 5 + 0) * 32 + b] + b_ih[c] + b_hh[c];
      const float xz = gout[(c4o * 5 + 1) * 32 + b] + b_ih[NC + c] + b_hh[NC + c];
      const float xn = gout[(c4o * 5 + 2) * 32 + b] + b_ih[2 * NC + c];
      const float hn = gout[(c4o * 5 + 3) * 32 + b] + b_hh[2 * NC + c];
      const float r = fsig(xr), z = fsig(xz);
      const float n = ftanh(xn + r * hn);
      const float hnew = (1.f - z) * n + z * h_prev[c * 32 + b];
      h_cur[c * 32 + b] = hnew;
      tredl[c4o * 32 + b] = w_t2[c] * ftanh(gout[(c4o * 5 + 4) * 32 + b] + b_t1[c]);
    }
    __syncthreads();
    if (tid < NB)
      TPART[bid * NB + tid] = tredl[tid] + tredl[32 + tid] + tredl[64 + tid] + tredl[96 + tid];
    gbarrier(bar, ph);

    // ========================== Phase Q ==========================
    {  // q[b][jq] = h_new[b,:] @ w_q[jq,:]; block owns 2 output columns
      const int ks = tid >> 6, sub = tid & 63;
      const int jx = sub >> 5, b = sub & 31;
      const int jq = bid * 2 + jx;
      const float* wqr = w_q + (size_t)jq * NC;
      const int kbase = ks * 128;
      float acc = 0.f;
      for (int k = 0; k < 128; ++k)
        acc += h_cur[(kbase + k) * 32 + b] * wqr[kbase + k];
      qpart[ks * 64 + sub] = acc;
    }
    __syncthreads();
    if (tid < 64) {
      float s = 0.f;
      #pragma unroll
      for (int ks = 0; ks < 8; ++ks) s += qpart[ks * 64 + tid];
      QBUF[(size_t)(tid & 31) * NC2 + bid * 2 + (tid >> 5)] = s;
    }
    if (bid < NB) {  // reduce trans partials for batch b = bid
      red[tid] = (tid < NBLK) ? TPART[tid * NB + bid] : 0.f;
      __syncthreads();
      if (tid < 64) {
        float s = red[tid] + red[64 + tid] + red[128 + tid] + red[192 + tid];
        #pragma unroll
        for (int off = 32; off > 0; off >>= 1) s += __shfl_down(s, off);
        if (tid == 0) TRED[bid] = s;
      }
    }
    gbarrier(bar, ph);

    // ========================== Phase B ==========================
    {
      const int b = bid >> 3, rch = bid & 7, s0 = rch * 32;
      const float invSE = 1.f / se_prev[b];
      const float invSW = 1.f / sw_prev[b];
      const float tr = (j == 0) ? 0.5f : fsig(TRED[b]);
      if (tid < 62) {  // align window (zero-padded conv halo)
        const int sp = s0 + tid - 15;
        alignl[tid] = (sp >= 0 && sp < NS) ? e_prev[b * NS + sp] * invSE : 0.f;
      }
      if (tid >= 64 && tid < 97) {  // alpha_{j-1} halo for the shift term
        const int i2 = tid - 64, sp = s0 + i2 - 1;
        wl2[i2] = (sp >= 0 && sp < NS) ? w_prev[b * NS + sp] * invSW : 0.f;
      }
      __syncthreads();
      const int wvx = tid >> 6, lane = tid & 63;
      const int c2 = wvx * 64 + lane;  // each wave owns a 64-channel chunk
      float wc[31];
      #pragma unroll
      for (int k = 0; k < 31; ++k) wc[k] = wcomb[k * NC2 + c2];
      const float wag = w_agg[c2];
      const float qv = QBUF[(size_t)b * NC2 + c2];
      float al[62];
      #pragma unroll
      for (int x = 0; x < 62; ++x) al[x] = alignl[x];
      const float* keyrow = keyT + ((size_t)(b * NS + s0)) * NC2 + c2;
      #pragma unroll
      for (int sl = 0; sl < 32; ++sl) {
        float conv = 0.f;
        #pragma unroll
        for (int k = 0; k < 31; ++k) conv += wc[k] * al[sl + k];
        float pe = wag * ftanh(conv + qv + keyrow[(size_t)sl * NC2]);
        #pragma unroll
        for (int off = 32; off > 0; off >>= 1) pe += __shfl_down(pe, off);
        if (lane == 0) Epart[sl * 9 + wvx] = pe;
      }
      __syncthreads();
      if (tid < 32) {  // finalize energies for this block's 32 s-positions
        const int sl = tid, s = s0 + sl;
        float Ev = 0.f;
        #pragma unroll
        for (int w8 = 0; w8 < 8; ++w8) Ev += Epart[sl * 9 + w8];
        const float ev = (mask[b * NS + s] != 0.f) ? __expf(Ev) : 0.f;
        const float csv = (1.f - tr) * wl2[sl + 1] + tr * wl2[sl] + 1e-7f;
        const float wvv = csv * ev;
        e_cur[b * NS + s] = ev;
        w_cur[b * NS + s] = wvv;
        wstash[sl] = wvv;
        float se = ev, sw2 = wvv;
        #pragma unroll
        for (int off = 16; off > 0; off >>= 1) {
          se += __shfl_down(se, off, 32);
          sw2 += __shfl_down(sw2, off, 32);
        }
        if (sl == 0) { atomicAdd(&se_cur[b], se); atomicAdd(&sw_cur[b], sw2); }
      }
      __syncthreads();
      {  // prevU_i += sum_{s chunk} w_s * enc[b,s,i]  (unnormalized attend)
        float acc = 0.f;
        const float* encb = enc + ((size_t)(b * NS + s0)) * NI + tid;
        #pragma unroll 8
        for (int ss = 0; ss < 32; ++ss) acc += wstash[ss] * encb[(size_t)ss * NI];
        atomicAdd(&pu_cur[tid * 32 + b], acc);
      }
      if (j < NT - 1) {  // stage next-step query / this-step frame, k-major
        if (rch == 0 && tid < NHq)
          XQ[(size_t)p * NHq * NB + tid * 32 + b] = queries[((size_t)b * NT + (j + 1)) * NHq + tid];
        if (rch == 1 && tid < NM)
          XF[(size_t)p * NM * NB + tid * 32 + b] = outputs[((size_t)b * NT + j) * NM + tid];
      }
    }
    gbarrier(bar, ph);
  }

  // epilogue: emit alpha_{T-1} (parity 1 since T-1 = 799 is odd)
  if (bid < NB && tid < NS) {
    const float invSW = 1.f / SWB[NB + bid];
    out[((size_t)bid * NT + (NT - 1)) * NS + tid] = WBUF[(size_t)NB * NS + bid * NS + tid] * invSW;
  }
}

// ---------------------------------------------------------------------------
extern "C" void kernel_launch(void* const* d_in, const int* in_sizes, int n_in,
                              void* d_out, int out_size, void* d_ws, size_t ws_size,
                              hipStream_t stream) {
  const float* enc     = (const float*)d_in[0];
  const float* queries = (const float*)d_in[1];
  const float* outputs = (const float*)d_in[2];
  const float* mask    = (const float*)d_in[3];
  const float* w_ih    = (const float*)d_in[4];
  const float* w_hh    = (const float*)d_in[5];
  const float* b_ih    = (const float*)d_in[6];
  const float* b_hh    = (const float*)d_in[7];
  const float* w_q     = (const float*)d_in[8];
  const float* w_loc1  = (const float*)d_in[9];
  const float* w_loc2  = (const float*)d_in[10];
  const float* w_k     = (const float*)d_in[11];
  const float* b_k     = (const float*)d_in[12];
  const float* w_agg   = (const float*)d_in[13];
  const float* w_t1    = (const float*)d_in[14];
  const float* b_t1    = (const float*)d_in[15];
  const float* w_t2    = (const float*)d_in[16];
  float* ws = (float*)d_ws;
  float* out = (float*)d_out;
  (void)in_sizes; (void)n_in; (void)out_size; (void)ws_size;

  k_init<<<dim3(1024), dim3(256), 0, stream>>>(enc, queries, w_ih, w_hh, w_t1,
                                               w_loc1, w_loc2, w_k, ws);
  k_key<<<dim3(NBLK), dim3(NTHR), 0, stream>>>(enc, b_k, ws);
  k_main<<<dim3(NBLK), dim3(NTHR), 0, stream>>>(enc, queries, outputs, mask, b_ih, b_hh,
                                                w_q, w_agg, b_t1, w_t2, ws, out);
}

// Round 2
// 111110.291 us; speedup vs baseline: 1.5251x; 1.5251x over previous
//
#include <hip/hip_runtime.h>
#include <cstdint>
#include <cstddef>

// ============================================================================
// Aligner (forward attention + GRU), persistent-kernel, MFMA-bf16 edition.
//
// Per step j, 3 device-barrier phases:
//  PA: X[32,1920](bf16) x Wcat[1920,4096](bf16, persistent in VGPRs) via
//      mfma_f32_16x16x32_bf16. K split across 4 wave-groups aligned to the
//      q(0:256)/prev(256:768)/h(768:1792)/frame(1792:1920) boundaries; the
//      prev range accumulates in a SEPARATE C fragment so the 1/sum(w)
//      normalization is applied post-reduce (PB's atomics stay unnormalized).
//      GRU update -> h (fp32 state + bf16 copy), trans partials.
//  PQ: blocks 0..31: q = h @ w_q^T via MFMA; blocks 64..95: trans reduce.
//  PB: location-conv (regs) + q + key(LDS bf16, persistent) -> energy ->
//      e=exp(E); alpha ~ ((1-t)a + t a_shift + 1e-7)*e (softmax denom
//      cancels); accumulate Sum_e, Sum_w, prevU via atomics.
// ============================================================================

namespace cfg {
constexpr int NB = 32, NS = 256, NI = 512, NHq = 256, NM = 80;
constexpr int NC = 1024, NC2 = 512, NT = 800;
constexpr int NBLK = 256, NTHR = 512;

constexpr size_t OFF_KEYT  = 0;                                   // 32*256*512 f32
constexpr size_t OFF_WKT   = OFF_KEYT + (size_t)NB * NS * NC2;    // 512*512 f32
constexpr size_t OFF_PU    = OFF_WKT + (size_t)NI * NC2;          // 2*32*512 f32 [b][i]
constexpr size_t OFF_H     = OFF_PU + (size_t)2 * NB * NI;        // 2*1024*32 f32 [c][b]
constexpr size_t OFF_H16   = OFF_H + (size_t)2 * NC * NB;         // 2*32*1024 u16 [b][c]
constexpr size_t OFF_E     = OFF_H16 + (size_t)NB * NC;           // 2*32*256 f32
constexpr size_t OFF_W     = OFF_E + (size_t)2 * NB * NS;         // 2*32*256 f32
constexpr size_t OFF_SE    = OFF_W + (size_t)2 * NB * NS;         // 64
constexpr size_t OFF_SW    = OFF_SE + 64;                         // 64
constexpr size_t OFF_TPART = OFF_SW + 64;                         // 256*32
constexpr size_t OFF_TRED  = OFF_TPART + (size_t)NBLK * NB;       // 32
constexpr size_t OFF_QBUF  = OFF_TRED + 32;                       // 32*512
constexpr size_t OFF_BAR   = OFF_QBUF + (size_t)NB * NC2;         // 256 uints
constexpr size_t OFF_Q16   = OFF_BAR + 256;                       // 800*32*256 u16
constexpr size_t OFF_F16   = OFF_Q16 + (size_t)NT * NB * NHq / 2; // 800*32*128 u16
constexpr size_t WS_FLOATS = OFF_F16 + (size_t)NT * NB * 128 / 2;
}
using namespace cfg;

typedef __attribute__((ext_vector_type(8))) short short8;
typedef __attribute__((ext_vector_type(4))) float f32x4;

__device__ __forceinline__ float frcp(float x) {
#if __has_builtin(__builtin_amdgcn_rcpf)
  return __builtin_amdgcn_rcpf(x);
#else
  return 1.f / x;
#endif
}
__device__ __forceinline__ float fsig(float x) { return frcp(1.f + __expf(-x)); }
__device__ __forceinline__ float ftanh(float x) {
  const float e = __expf(2.f * x);
  return 1.f - 2.f * frcp(e + 1.f);
}
__device__ __forceinline__ short f2bf(float f) {  // RNE f32 -> bf16 bits
  unsigned u = __float_as_uint(f);
  u += 0x7FFFu + ((u >> 16) & 1u);
  return (short)(u >> 16);
}
__device__ __forceinline__ float bf2f(short s) {
  return __uint_as_float(((unsigned)(unsigned short)s) << 16);
}

// Two-level barrier among 256 co-resident blocks (8 groups of 32).
__device__ __forceinline__ void gbarrier(unsigned* bar, int& ph) {
  ++ph;
  __syncthreads();
  if (threadIdx.x == 0) {
    __threadfence();
    const int g = blockIdx.x >> 5;
    const unsigned old = atomicAdd(&bar[(1 + g) * 16], 1u);
    if (old == 32u * (unsigned)ph - 1u) atomicAdd(&bar[0], 1u);
    const unsigned tgt = 8u * (unsigned)ph;
    while (__hip_atomic_load(&bar[0], __ATOMIC_RELAXED, __HIP_MEMORY_SCOPE_AGENT) < tgt)
      __builtin_amdgcn_s_sleep(2);
  }
  __syncthreads();
  __threadfence();
}

// Wcat element (kind: 0=r,1=z,2=n,3=tp; c: channel; k: 0..1919)
__device__ __forceinline__ float wcat_val(const float* __restrict__ w_ih,
                                          const float* __restrict__ w_hh,
                                          const float* __restrict__ w_t1,
                                          int kind, int c, int k) {
  if (kind < 3) {
    const int gr = kind * NC + c;
    if (k < 768) return w_ih[(size_t)gr * 768 + k];
    if (k < 1792) return w_hh[(size_t)gr * NC + (k - 768)];
    return 0.f;
  }
  if (k >= 256 && k < 768) return w_t1[(size_t)c * 1616 + (k - 256)];
  if (k >= 768 && k < 1792) return w_t1[(size_t)c * 1616 + 592 + (k - 768)];
  if (k >= 1792 && k < 1872) return w_t1[(size_t)c * 1616 + 512 + (k - 1792)];
  return 0.f;
}

// A-fragment loader for K-step S (32 k). Lane holds X[b][S*32+kg*8 .. +8].
template <int S>
__device__ __forceinline__ short8 load_afrag(int j, const unsigned short* __restrict__ Q16,
                                             const unsigned short* __restrict__ F16,
                                             const unsigned short* __restrict__ hb16_prev,
                                             const float* __restrict__ pu_prev,
                                             int b, int kg) {
  if constexpr (S < 8) {  // query
    return *(const short8*)(Q16 + ((size_t)j * NB + b) * NHq + S * 32 + kg * 8);
  } else if constexpr (S < 24) {  // prev (unnormalized, fp32 -> bf16)
    const float* p = pu_prev + (size_t)b * NI + (S * 32 - 256) + kg * 8;
    const float4 lo = *(const float4*)p;
    const float4 hi = *(const float4*)(p + 4);
    short8 a;
    a[0] = f2bf(lo.x); a[1] = f2bf(lo.y); a[2] = f2bf(lo.z); a[3] = f2bf(lo.w);
    a[4] = f2bf(hi.x); a[5] = f2bf(hi.y); a[6] = f2bf(hi.z); a[7] = f2bf(hi.w);
    return a;
  } else if constexpr (S < 56) {  // h
    return *(const short8*)(hb16_prev + (size_t)b * NC + (S * 32 - 768) + kg * 8);
  } else {  // frame (j-1); zero at j==0
    if (j == 0) { short8 z = {0, 0, 0, 0, 0, 0, 0, 0}; return z; }
    return *(const short8*)(F16 + ((size_t)(j - 1) * NB + b) * 128 + (S * 32 - 1792) + kg * 8);
  }
}

// ---------------------------------------------------------------------------
__global__ void k_init(const float* __restrict__ enc, const float* __restrict__ queries,
                       const float* __restrict__ outputs, const float* __restrict__ w_k,
                       float* __restrict__ ws) {
  const size_t t0 = (size_t)blockIdx.x * blockDim.x + threadIdx.x;
  const size_t gs = (size_t)gridDim.x * blockDim.x;
  // w_kT[i][c2]
  for (size_t x = t0; x < (size_t)NI * NC2; x += gs) {
    const int i = (int)(x / NC2), c2 = (int)(x % NC2);
    ws[OFF_WKT + x] = w_k[(size_t)c2 * NI + i];
  }
  // PU parity1 = enc[b,0,:]  (alpha_init one-hot at s=0, SW=1); parity0 = 0
  for (size_t x = t0; x < (size_t)NB * NI; x += gs) {
    const int b = (int)(x / NI), i = (int)(x % NI);
    ws[OFF_PU + x] = 0.f;
    ws[OFF_PU + (size_t)NB * NI + b * NI + i] = enc[(size_t)b * NS * NI + i];
  }
  // h fp32 + bf16 zeros (both parities)
  for (size_t x = t0; x < (size_t)2 * NC * NB; x += gs) ws[OFF_H + x] = 0.f;
  for (size_t x = t0; x < (size_t)NB * NC; x += gs) ws[OFF_H16 + x] = 0.f;  // 2 parities as f32 slots
  // e parity1 = 1 (SE=256); w parity1 = one-hot (SW=1)
  for (size_t x = t0; x < (size_t)NB * NS; x += gs) {
    ws[OFF_E + x] = 0.f;
    ws[OFF_E + (size_t)NB * NS + x] = 1.f;
    ws[OFF_W + x] = 0.f;
    ws[OFF_W + (size_t)NB * NS + x] = ((x & (NS - 1)) == 0) ? 1.f : 0.f;
  }
  for (size_t x = t0; x < (size_t)NB; x += gs) {
    ws[OFF_SE + x] = 0.f; ws[OFF_SE + NB + x] = (float)NS;
    ws[OFF_SW + x] = 0.f; ws[OFF_SW + NB + x] = 1.f;
    ws[OFF_TRED + x] = 0.f;
  }
  unsigned* bar = (unsigned*)(ws + OFF_BAR);
  for (size_t x = t0; x < 256; x += gs) bar[x] = 0u;
  // Q16[t][b][k] bf16
  unsigned short* Q16 = (unsigned short*)(ws + OFF_Q16);
  for (size_t x = t0; x < (size_t)NT * NB * NHq; x += gs) {
    const int k = (int)(x & (NHq - 1));
    const int b = (int)((x >> 8) & (NB - 1));
    const int t = (int)(x >> 13);
    Q16[x] = (unsigned short)f2bf(queries[((size_t)b * NT + t) * NHq + k]);
  }
  // F16[t][b][k] bf16, padded 80->128 with zeros
  unsigned short* F16 = (unsigned short*)(ws + OFF_F16);
  for (size_t x = t0; x < (size_t)NT * NB * 128; x += gs) {
    const int k = (int)(x & 127);
    const int b = (int)((x >> 7) & (NB - 1));
    const int t = (int)(x >> 12);
    F16[x] = (k < NM) ? (unsigned short)f2bf(outputs[((size_t)b * NT + t) * NM + k]) : 0;
  }
}

// ---------------------------------------------------------------------------
// keyT[b][s][c2] = enc[b,s,:] @ w_k^T + b_k
__global__ __launch_bounds__(NTHR) void k_key(const float* __restrict__ enc,
                                              const float* __restrict__ b_k,
                                              float* __restrict__ ws) {
  __shared__ float encl[4 * NI];
  const int bid = blockIdx.x, tid = threadIdx.x;
  const int b = bid >> 3, s0 = (bid & 7) * 32;
  const float* wkT = ws + OFF_WKT;
  float* keyT = ws + OFF_KEYT;
  const float bk = b_k[tid];
  for (int q = 0; q < 8; ++q) {
    const int sb = s0 + q * 4;
    for (int x = tid; x < 4 * NI; x += NTHR) {
      const int ss = x >> 9, i = x & (NI - 1);
      encl[x] = enc[((size_t)(b * NS + sb + ss)) * NI + i];
    }
    __syncthreads();
    float a0 = bk, a1 = bk, a2 = bk, a3 = bk;
    for (int i = 0; i < NI; ++i) {
      const float wv = wkT[(size_t)i * NC2 + tid];
      a0 += wv * encl[i];           a1 += wv * encl[NI + i];
      a2 += wv * encl[2 * NI + i];  a3 += wv * encl[3 * NI + i];
    }
    keyT[((size_t)(b * NS + sb + 0)) * NC2 + tid] = a0;
    keyT[((size_t)(b * NS + sb + 1)) * NC2 + tid] = a1;
    keyT[((size_t)(b * NS + sb + 2)) * NC2 + tid] = a2;
    keyT[((size_t)(b * NS + sb + 3)) * NC2 + tid] = a3;
    __syncthreads();
  }
}

// ---------------------------------------------------------------------------
__global__ __launch_bounds__(NTHR, 2) void k_main(
    const float* __restrict__ enc, const float* __restrict__ mask,
    const float* __restrict__ w_ih, const float* __restrict__ w_hh,
    const float* __restrict__ b_ih, const float* __restrict__ b_hh,
    const float* __restrict__ w_q, const float* __restrict__ w_loc1,
    const float* __restrict__ w_loc2, const float* __restrict__ w_agg,
    const float* __restrict__ w_t1, const float* __restrict__ b_t1,
    const float* __restrict__ w_t2, float* ws, float* __restrict__ out) {
  const int bid = blockIdx.x, tid = threadIdx.x;
  float* const keyT = ws + OFF_KEYT;
  float* const PU = ws + OFF_PU;
  float* const HB = ws + OFF_H;
  unsigned short* const HB16 = (unsigned short*)(ws + OFF_H16);
  float* const EB = ws + OFF_E;
  float* const WBUF = ws + OFF_W;
  float* const SEB = ws + OFF_SE;
  float* const SWB = ws + OFF_SW;
  float* const TPART = ws + OFF_TPART;
  float* const TRED = ws + OFF_TRED;
  float* const QBUF = ws + OFF_QBUF;
  unsigned* const bar = (unsigned*)(ws + OFF_BAR);
  const unsigned short* const Q16 = (const unsigned short*)(ws + OFF_Q16);
  const unsigned short* const F16 = (const unsigned short*)(ws + OFF_F16);

  __shared__ unsigned short keyl[NC2 * 32];  // 32 KB, persistent key slice (bf16)
  __shared__ float Cred[2 * 5 * 4 * 64];     // 10 KB, MFMA cross-wave reduce (PQ reuses)
  __shared__ float gout2[5 * 4 * 32];        // r,z,nx,nh,tp per (c4,b)
  __shared__ float swinv_l[32];
  __shared__ float tredl[128];
  __shared__ float alignl[64];
  __shared__ float wl2[34];
  __shared__ float Epart[32 * 9];
  __shared__ float wstash[32];

  const int lane = tid & 63, wv = tid >> 6;
  const int m2 = wv >> 2, k4 = wv & 3;        // PA roles
  const int kg = lane >> 4;                   // A/B fragment k-group
  const int ab = m2 * 16 + (lane & 15);       // A batch index for this lane
  const int cs = bid * 4;                     // block's 4 GRU channels
  const int pb_b = bid >> 3, pb_s0 = (bid & 7) * 32;  // PB roles
  int ph = 0;

  // ---- one-time staging -------------------------------------------------
  // B-fragments of Wcat, persistent in VGPRs: wreg[si] for this wave's steps.
  short8 wreg[16];
  {
    const int n = lane & 15;
    const int kind = n >> 2, ch = cs + (n & 3);
#pragma unroll
    for (int si = 0; si < 16; ++si) {
      int s = (k4 == 0) ? (si < 8 ? si : (si < 15 ? 16 + si : -1))
            : (k4 == 1) ? 8 + si
            : (k4 == 2) ? (si < 15 ? 31 + si : -1)
                        : (si < 14 ? 46 + si : -1);
      short8 w = {0, 0, 0, 0, 0, 0, 0, 0};
      if (s >= 0) {
        const int k0 = s * 32 + kg * 8;
#pragma unroll
        for (int jj = 0; jj < 8; ++jj)
          w[jj] = f2bf(wcat_val(w_ih, w_hh, w_t1, kind, ch, k0 + jj));
      }
      wreg[si] = w;
    }
  }
  // location-conv weights (fused 31x512), per-thread c2 = tid
  float wc[31];
#pragma unroll
  for (int k = 0; k < 31; ++k) {
    float s = 0.f;
    for (int l = 0; l < 32; ++l) s += w_loc2[tid * 32 + l] * w_loc1[l * 31 + k];
    wc[k] = s;
  }
  const float wag = w_agg[tid];
  // key slice -> LDS bf16, layout [c2][sl]
  for (int x = tid; x < NC2 * 32; x += NTHR) {
    const int sl = x >> 9, c2s = x & (NC2 - 1);
    keyl[c2s * 32 + sl] =
        (unsigned short)f2bf(keyT[((size_t)(pb_b * NS + pb_s0 + sl)) * NC2 + c2s]);
  }
  __syncthreads();

  for (int j = 0; j < NT; ++j) {
    const int p = j & 1;
    const float* pu_prev = PU + (size_t)(1 - p) * NB * NI;
    float* pu_cur = PU + (size_t)p * NB * NI;
    const float* h_prev = HB + (size_t)(1 - p) * NC * NB;
    float* h_cur = HB + (size_t)p * NC * NB;
    const unsigned short* hb16_prev = HB16 + (size_t)(1 - p) * NB * NC;
    unsigned short* hb16_cur = HB16 + (size_t)p * NB * NC;
    const float* e_prev = EB + (size_t)(1 - p) * NB * NS;
    float* e_cur = EB + (size_t)p * NB * NS;
    const float* w_prev = WBUF + (size_t)(1 - p) * NB * NS;
    float* w_cur = WBUF + (size_t)p * NB * NS;
    const float* se_prev = SEB + (size_t)(1 - p) * NB;
    float* se_cur = SEB + (size_t)p * NB;
    const float* sw_prev = SWB + (size_t)(1 - p) * NB;
    float* sw_cur = SWB + (size_t)p * NB;

    // ========================== Phase A ==========================
    if (tid < 64) pu_cur[bid * 64 + tid] = 0.f;
    if (bid == 0 && tid < NB) se_cur[tid] = 0.f;
    if (bid == 1 && tid < NB) sw_cur[tid] = 0.f;
    if (tid < NB) swinv_l[tid] = 1.f / sw_prev[tid];
    __syncthreads();

    if (j >= 1 && bid < NB && tid < NS)
      out[((size_t)bid * NT + (j - 1)) * NS + tid] = w_prev[bid * NS + tid] * swinv_l[bid];

    f32x4 accA = {0.f, 0.f, 0.f, 0.f}, accB = {0.f, 0.f, 0.f, 0.f};
#define PA_STEP(SI, S, ACC)                                                   \
  {                                                                           \
    short8 afrag = load_afrag<S>(j, Q16, F16, hb16_prev, pu_prev, ab, kg);    \
    ACC = __builtin_amdgcn_mfma_f32_16x16x32_bf16(afrag, wreg[SI], ACC, 0, 0, 0); \
  }
    if (k4 == 0) {
      PA_STEP(0, 0, accA)  PA_STEP(1, 1, accA)  PA_STEP(2, 2, accA)  PA_STEP(3, 3, accA)
      PA_STEP(4, 4, accA)  PA_STEP(5, 5, accA)  PA_STEP(6, 6, accA)  PA_STEP(7, 7, accA)
      PA_STEP(8, 24, accB) PA_STEP(9, 25, accB) PA_STEP(10, 26, accB) PA_STEP(11, 27, accB)
      PA_STEP(12, 28, accB) PA_STEP(13, 29, accB) PA_STEP(14, 30, accB)
    } else if (k4 == 1) {
      PA_STEP(0, 8, accA)  PA_STEP(1, 9, accA)  PA_STEP(2, 10, accA) PA_STEP(3, 11, accA)
      PA_STEP(4, 12, accA) PA_STEP(5, 13, accA) PA_STEP(6, 14, accA) PA_STEP(7, 15, accA)
      PA_STEP(8, 16, accA) PA_STEP(9, 17, accA) PA_STEP(10, 18, accA) PA_STEP(11, 19, accA)
      PA_STEP(12, 20, accA) PA_STEP(13, 21, accA) PA_STEP(14, 22, accA) PA_STEP(15, 23, accA)
    } else if (k4 == 2) {
      PA_STEP(0, 31, accA) PA_STEP(1, 32, accA) PA_STEP(2, 33, accA) PA_STEP(3, 34, accA)
      PA_STEP(4, 35, accA) PA_STEP(5, 36, accA) PA_STEP(6, 37, accA) PA_STEP(7, 38, accA)
      PA_STEP(8, 39, accA) PA_STEP(9, 40, accA) PA_STEP(10, 41, accA) PA_STEP(11, 42, accA)
      PA_STEP(12, 43, accA) PA_STEP(13, 44, accA) PA_STEP(14, 45, accA)
    } else {
      PA_STEP(0, 46, accA) PA_STEP(1, 47, accA) PA_STEP(2, 48, accA) PA_STEP(3, 49, accA)
      PA_STEP(4, 50, accA) PA_STEP(5, 51, accA) PA_STEP(6, 52, accA) PA_STEP(7, 53, accA)
      PA_STEP(8, 54, accA) PA_STEP(9, 55, accA) PA_STEP(10, 56, accA) PA_STEP(11, 57, accA)
      PA_STEP(12, 58, accA) PA_STEP(13, 59, accA)
    }
#undef PA_STEP
    // Cred[m2][sg][r][lane]: sg 0=w0.A(q) 1=w0.B(h-part) 2=w1.A(prev) 3=w2.A 4=w3.A
    {
      auto cidx = [](int m, int sg, int r, int l) { return ((m * 5 + sg) * 4 + r) * 64 + l; };
      if (k4 == 0) {
#pragma unroll
        for (int r = 0; r < 4; ++r) {
          Cred[cidx(m2, 0, r, lane)] = accA[r];
          Cred[cidx(m2, 1, r, lane)] = accB[r];
        }
      } else {
        const int sg = 1 + k4;
#pragma unroll
        for (int r = 0; r < 4; ++r) Cred[cidx(m2, sg, r, lane)] = accA[r];
      }
    }
    __syncthreads();
    {  // combine: gate = s0 + swinv*s1 + s2  (n-gate keeps x/h split)
      const int n = tid & 15, b = tid >> 4;
      const int m2r = b >> 4, bm = b & 15, l = (bm >> 2) * 16 + n, r = bm & 3;
      auto cidx = [](int m, int sg, int rr, int ll) { return ((m * 5 + sg) * 4 + rr) * 64 + ll; };
      const float s0 = Cred[cidx(m2r, 0, r, l)];
      const float sB = Cred[cidx(m2r, 1, r, l)];
      const float s1 = Cred[cidx(m2r, 2, r, l)];
      const float s2 = sB + Cred[cidx(m2r, 3, r, l)] + Cred[cidx(m2r, 4, r, l)];
      const float swv = swinv_l[b];
      const int kind = n >> 2, c4o = n & 3;
      if (kind == 2) {
        gout2[2 * 128 + c4o * 32 + b] = s0 + swv * s1;
        gout2[3 * 128 + c4o * 32 + b] = s2;
      } else {
        const int slot = (kind == 3) ? 4 : kind;
        gout2[slot * 128 + c4o * 32 + b] = s0 + swv * s1 + s2;
      }
    }
    __syncthreads();
    if (tid < 128) {  // GRU update, 4 channels x 32 batches
      const int c4o = tid >> 5, b = tid & 31, c = cs + c4o;
      const float xr = gout2[0 * 128 + c4o * 32 + b] + b_ih[c] + b_hh[c];
      const float xz = gout2[1 * 128 + c4o * 32 + b] + b_ih[NC + c] + b_hh[NC + c];
      const float xn = gout2[2 * 128 + c4o * 32 + b] + b_ih[2 * NC + c];
      const float hn = gout2[3 * 128 + c4o * 32 + b] + b_hh[2 * NC + c];
      const float tp = gout2[4 * 128 + c4o * 32 + b];
      const float r = fsig(xr), z = fsig(xz);
      const float nn = ftanh(xn + r * hn);
      const float hnew = (1.f - z) * nn + z * h_prev[c * 32 + b];
      h_cur[c * 32 + b] = hnew;
      hb16_cur[(size_t)b * NC + c] = (unsigned short)f2bf(hnew);
      tredl[c4o * 32 + b] = w_t2[c] * ftanh(tp + b_t1[c]);
    }
    __syncthreads();
    if (tid < NB)
      TPART[bid * NB + tid] = tredl[tid] + tredl[32 + tid] + tredl[64 + tid] + tredl[96 + tid];
    gbarrier(bar, ph);

    // ========================== Phase Q ==========================
    if (bid < 32) {  // q = h_new @ w_q^T via MFMA; block owns 16 q-cols
      f32x4 qacc = {0.f, 0.f, 0.f, 0.f};
      const unsigned short* hb = HB16 + (size_t)p * NB * NC;
      const int col = lane & 15;
      const int jq = bid * 16 + col;
      for (int ks = 0; ks < 8; ++ks) {
        const int s = k4 * 8 + ks;
        const short8 a = *(const short8*)(hb + (size_t)ab * NC + s * 32 + kg * 8);
        const float* wp = w_q + (size_t)jq * NC + s * 32 + kg * 8;
        const float4 lo = *(const float4*)wp;
        const float4 hi = *(const float4*)(wp + 4);
        short8 bf;
        bf[0] = f2bf(lo.x); bf[1] = f2bf(lo.y); bf[2] = f2bf(lo.z); bf[3] = f2bf(lo.w);
        bf[4] = f2bf(hi.x); bf[5] = f2bf(hi.y); bf[6] = f2bf(hi.z); bf[7] = f2bf(hi.w);
        qacc = __builtin_amdgcn_mfma_f32_16x16x32_bf16(a, bf, qacc, 0, 0, 0);
      }
#pragma unroll
      for (int r = 0; r < 4; ++r) Cred[((m2 * 4 + k4) * 4 + r) * 64 + lane] = qacc[r];
      __syncthreads();
      {
        const int col2 = tid & 15, b2 = tid >> 4;
        const int m2r = b2 >> 4, bm = b2 & 15, l = (bm >> 2) * 16 + col2, r = bm & 3;
        float s = 0.f;
#pragma unroll
        for (int kk = 0; kk < 4; ++kk) s += Cred[((m2r * 4 + kk) * 4 + r) * 64 + l];
        QBUF[(size_t)b2 * NC2 + bid * 16 + col2] = s;
      }
    } else if (bid >= 64 && bid < 96) {  // trans reduce for batch b = bid-64
      const int b2 = bid - 64;
      float v = (tid < NBLK) ? TPART[tid * NB + b2] : 0.f;
#pragma unroll
      for (int off = 32; off > 0; off >>= 1) v += __shfl_down(v, off);
      if (lane == 0) Cred[wv] = v;
      __syncthreads();
      if (tid == 0) {
        float s = 0.f;
#pragma unroll
        for (int w8 = 0; w8 < 8; ++w8) s += Cred[w8];
        TRED[b2] = s;
      }
    }
    gbarrier(bar, ph);

    // ========================== Phase B ==========================
    {
      const int b = pb_b, s0 = pb_s0;
      const float invSE = 1.f / se_prev[b];
      const float invSW = 1.f / sw_prev[b];
      const float tr = (j == 0) ? 0.5f : fsig(TRED[b]);
      if (tid < 62) {  // align window (zero-padded conv halo)
        const int sp = s0 + tid - 15;
        alignl[tid] = (sp >= 0 && sp < NS) ? e_prev[b * NS + sp] * invSE : 0.f;
      }
      if (tid >= 64 && tid < 97) {  // alpha_{j-1} halo for the shift term
        const int i2 = tid - 64, sp = s0 + i2 - 1;
        wl2[i2] = (sp >= 0 && sp < NS) ? w_prev[b * NS + sp] * invSW : 0.f;
      }
      __syncthreads();
      const int wvx = wv;  // wave owns c2 = tid (64-channel chunk per wave)
      const float qv = QBUF[(size_t)b * NC2 + tid];
      float al[62];
#pragma unroll
      for (int x = 0; x < 62; ++x) al[x] = alignl[x];
#pragma unroll
      for (int sl8 = 0; sl8 < 4; ++sl8) {
        const short8 kk = *(const short8*)&keyl[tid * 32 + sl8 * 8];
#pragma unroll
        for (int i = 0; i < 8; ++i) {
          const int sl = sl8 * 8 + i;
          float conv = 0.f;
#pragma unroll
          for (int k = 0; k < 31; ++k) conv += wc[k] * al[sl + k];
          float pe = wag * ftanh(conv + qv + bf2f(kk[i]));
#pragma unroll
          for (int off = 32; off > 0; off >>= 1) pe += __shfl_down(pe, off);
          if (lane == 0) Epart[sl * 9 + wvx] = pe;
        }
      }
      __syncthreads();
      if (tid < 32) {  // finalize energies for this block's 32 s-positions
        const int sl = tid, s = s0 + sl;
        float Ev = 0.f;
#pragma unroll
        for (int w8 = 0; w8 < 8; ++w8) Ev += Epart[sl * 9 + w8];
        const float ev = (mask[b * NS + s] != 0.f) ? __expf(Ev) : 0.f;
        const float csv = (1.f - tr) * wl2[sl + 1] + tr * wl2[sl] + 1e-7f;
        const float wvv = csv * ev;
        e_cur[b * NS + s] = ev;
        w_cur[b * NS + s] = wvv;
        wstash[sl] = wvv;
        float se = ev, sw2 = wvv;
#pragma unroll
        for (int off = 16; off > 0; off >>= 1) {
          se += __shfl_down(se, off, 32);
          sw2 += __shfl_down(sw2, off, 32);
        }
        if (sl == 0) { atomicAdd(&se_cur[b], se); atomicAdd(&sw_cur[b], sw2); }
      }
      __syncthreads();
      {  // prevU[b][i] += sum_s w_s * enc[b,s,i]
        float acc = 0.f;
        const float* encb = enc + ((size_t)(b * NS + s0)) * NI + tid;
#pragma unroll 8
        for (int ss = 0; ss < 32; ++ss) acc += wstash[ss] * encb[(size_t)ss * NI];
        atomicAdd(&pu_cur[(size_t)b * NI + tid], acc);
      }
    }
    gbarrier(bar, ph);
  }

  // epilogue: alpha_{T-1} (parity 1 since 799 is odd)
  if (bid < NB && tid < NS) {
    const float invSW = 1.f / SWB[NB + bid];
    out[((size_t)bid * NT + (NT - 1)) * NS + tid] =
        WBUF[(size_t)NB * NS + bid * NS + tid] * invSW;
  }
}

// ---------------------------------------------------------------------------
extern "C" void kernel_launch(void* const* d_in, const int* in_sizes, int n_in,
                              void* d_out, int out_size, void* d_ws, size_t ws_size,
                              hipStream_t stream) {
  const float* enc     = (const float*)d_in[0];
  const float* queries = (const float*)d_in[1];
  const float* outputs = (const float*)d_in[2];
  const float* mask    = (const float*)d_in[3];
  const float* w_ih    = (const float*)d_in[4];
  const float* w_hh    = (const float*)d_in[5];
  const float* b_ih    = (const float*)d_in[6];
  const float* b_hh    = (const float*)d_in[7];
  const float* w_q     = (const float*)d_in[8];
  const float* w_loc1  = (const float*)d_in[9];
  const float* w_loc2  = (const float*)d_in[10];
  const float* w_k     = (const float*)d_in[11];
  const float* b_k     = (const float*)d_in[12];
  const float* w_agg   = (const float*)d_in[13];
  const float* w_t1    = (const float*)d_in[14];
  const float* b_t1    = (const float*)d_in[15];
  const float* w_t2    = (const float*)d_in[16];
  float* ws = (float*)d_ws;
  float* out = (float*)d_out;
  (void)in_sizes; (void)n_in; (void)out_size; (void)ws_size;

  k_init<<<dim3(1024), dim3(256), 0, stream>>>(enc, queries, outputs, w_k, ws);
  k_key<<<dim3(NBLK), dim3(NTHR), 0, stream>>>(enc, b_k, ws);
  k_main<<<dim3(NBLK), dim3(NTHR), 0, stream>>>(enc, mask, w_ih, w_hh, b_ih, b_hh,
                                                w_q, w_loc1, w_loc2, w_agg, w_t1,
                                                b_t1, w_t2, ws, out);
}

// Round 4
// 45265.320 us; speedup vs baseline: 3.7436x; 2.4546x over previous
//
#include <hip/hip_runtime.h>
#include <cstdint>
#include <cstddef>

// ============================================================================
// Aligner (forward attention + GRU), persistent-kernel, MFMA-bf16 edition.
// Round 4 (= Round 3 with fixed fence spelling): thread0-only scoped fences
// in gbarrier via __builtin_amdgcn_fence (kills the per-wave
// buffer_wbl2/buffer_inv storm), conflict-free keyl stride (34 shorts),
// bf16 w_q for PQ.
// ============================================================================

namespace cfg {
constexpr int NB = 32, NS = 256, NI = 512, NHq = 256, NM = 80;
constexpr int NC = 1024, NC2 = 512, NT = 800;
constexpr int NBLK = 256, NTHR = 512;

constexpr size_t OFF_KEYT  = 0;                                   // 32*256*512 f32
constexpr size_t OFF_WKT   = OFF_KEYT + (size_t)NB * NS * NC2;    // 512*512 f32
constexpr size_t OFF_PU    = OFF_WKT + (size_t)NI * NC2;          // 2*32*512 f32 [b][i]
constexpr size_t OFF_H     = OFF_PU + (size_t)2 * NB * NI;        // 2*1024*32 f32 [c][b]
constexpr size_t OFF_H16   = OFF_H + (size_t)2 * NC * NB;         // 2*32*1024 u16 [b][c]
constexpr size_t OFF_E     = OFF_H16 + (size_t)NB * NC;           // 2*32*256 f32
constexpr size_t OFF_W     = OFF_E + (size_t)2 * NB * NS;         // 2*32*256 f32
constexpr size_t OFF_SE    = OFF_W + (size_t)2 * NB * NS;         // 64
constexpr size_t OFF_SW    = OFF_SE + 64;                         // 64
constexpr size_t OFF_TPART = OFF_SW + 64;                         // 256*32
constexpr size_t OFF_TRED  = OFF_TPART + (size_t)NBLK * NB;       // 32
constexpr size_t OFF_QBUF  = OFF_TRED + 32;                       // 32*512
constexpr size_t OFF_BAR   = OFF_QBUF + (size_t)NB * NC2;         // 256 uints
constexpr size_t OFF_Q16   = OFF_BAR + 256;                       // 800*32*256 u16
constexpr size_t OFF_F16   = OFF_Q16 + (size_t)NT * NB * NHq / 2; // 800*32*128 u16
constexpr size_t OFF_WQ16  = OFF_F16 + (size_t)NT * NB * 128 / 2; // 512*1024 u16
constexpr size_t WS_FLOATS = OFF_WQ16 + (size_t)NC2 * NC / 2;
constexpr int KLSTRIDE = 34;  // keyl leading stride in shorts (word stride 17, odd)
}
using namespace cfg;

typedef __attribute__((ext_vector_type(8))) short short8;
typedef __attribute__((ext_vector_type(4))) float f32x4;

__device__ __forceinline__ float frcp(float x) {
#if __has_builtin(__builtin_amdgcn_rcpf)
  return __builtin_amdgcn_rcpf(x);
#else
  return 1.f / x;
#endif
}
__device__ __forceinline__ float fsig(float x) { return frcp(1.f + __expf(-x)); }
__device__ __forceinline__ float ftanh(float x) {
  const float e = __expf(2.f * x);
  return 1.f - 2.f * frcp(e + 1.f);
}
__device__ __forceinline__ short f2bf(float f) {  // RNE f32 -> bf16 bits
  unsigned u = __float_as_uint(f);
  u += 0x7FFFu + ((u >> 16) & 1u);
  return (short)(u >> 16);
}
__device__ __forceinline__ float bf2f(short s) {
  return __uint_as_float(((unsigned)(unsigned short)s) << 16);
}

// Two-level barrier among 256 co-resident blocks (8 groups of 32).
// Fences are issued by ONE wave per block: buffer_wbl2/buffer_inv are
// cache-wide (L1 per-CU = shared by the whole block; L2 per-XCD), and
// __syncthreads has already drained every wave's stores (vmcnt(0) before
// s_barrier). Per-wave __threadfence here was ~95% of Round-2's runtime.
__device__ __forceinline__ void gbarrier(unsigned* bar, int& ph) {
  ++ph;
  __syncthreads();
  if (threadIdx.x == 0) {
    __builtin_amdgcn_fence(__ATOMIC_RELEASE, "agent");
    const int g = blockIdx.x >> 5;
    const unsigned old = atomicAdd(&bar[(1 + g) * 16], 1u);
    if (old == 32u * (unsigned)ph - 1u) atomicAdd(&bar[0], 1u);
    const unsigned tgt = 8u * (unsigned)ph;
    while (__hip_atomic_load(&bar[0], __ATOMIC_RELAXED, __HIP_MEMORY_SCOPE_AGENT) < tgt)
      __builtin_amdgcn_s_sleep(4);
    __builtin_amdgcn_fence(__ATOMIC_ACQUIRE, "agent");
  }
  __syncthreads();
}

// Wcat element (kind: 0=r,1=z,2=n,3=tp; c: channel; k: 0..1919)
__device__ __forceinline__ float wcat_val(const float* __restrict__ w_ih,
                                          const float* __restrict__ w_hh,
                                          const float* __restrict__ w_t1,
                                          int kind, int c, int k) {
  if (kind < 3) {
    const int gr = kind * NC + c;
    if (k < 768) return w_ih[(size_t)gr * 768 + k];
    if (k < 1792) return w_hh[(size_t)gr * NC + (k - 768)];
    return 0.f;
  }
  if (k >= 256 && k < 768) return w_t1[(size_t)c * 1616 + (k - 256)];
  if (k >= 768 && k < 1792) return w_t1[(size_t)c * 1616 + 592 + (k - 768)];
  if (k >= 1792 && k < 1872) return w_t1[(size_t)c * 1616 + 512 + (k - 1792)];
  return 0.f;
}

// A-fragment loader for K-step S (32 k). Lane holds X[b][S*32+kg*8 .. +8].
template <int S>
__device__ __forceinline__ short8 load_afrag(int j, const unsigned short* __restrict__ Q16,
                                             const unsigned short* __restrict__ F16,
                                             const unsigned short* __restrict__ hb16_prev,
                                             const float* __restrict__ pu_prev,
                                             int b, int kg) {
  if constexpr (S < 8) {  // query
    return *(const short8*)(Q16 + ((size_t)j * NB + b) * NHq + S * 32 + kg * 8);
  } else if constexpr (S < 24) {  // prev (unnormalized, fp32 -> bf16)
    const float* p = pu_prev + (size_t)b * NI + (S * 32 - 256) + kg * 8;
    const float4 lo = *(const float4*)p;
    const float4 hi = *(const float4*)(p + 4);
    short8 a;
    a[0] = f2bf(lo.x); a[1] = f2bf(lo.y); a[2] = f2bf(lo.z); a[3] = f2bf(lo.w);
    a[4] = f2bf(hi.x); a[5] = f2bf(hi.y); a[6] = f2bf(hi.z); a[7] = f2bf(hi.w);
    return a;
  } else if constexpr (S < 56) {  // h
    return *(const short8*)(hb16_prev + (size_t)b * NC + (S * 32 - 768) + kg * 8);
  } else {  // frame (j-1); zero at j==0
    if (j == 0) { short8 z = {0, 0, 0, 0, 0, 0, 0, 0}; return z; }
    return *(const short8*)(F16 + ((size_t)(j - 1) * NB + b) * 128 + (S * 32 - 1792) + kg * 8);
  }
}

// ---------------------------------------------------------------------------
__global__ void k_init(const float* __restrict__ enc, const float* __restrict__ queries,
                       const float* __restrict__ outputs, const float* __restrict__ w_k,
                       const float* __restrict__ w_q, float* __restrict__ ws) {
  const size_t t0 = (size_t)blockIdx.x * blockDim.x + threadIdx.x;
  const size_t gs = (size_t)gridDim.x * blockDim.x;
  // w_kT[i][c2]
  for (size_t x = t0; x < (size_t)NI * NC2; x += gs) {
    const int i = (int)(x / NC2), c2 = (int)(x % NC2);
    ws[OFF_WKT + x] = w_k[(size_t)c2 * NI + i];
  }
  // PU parity1 = enc[b,0,:]  (alpha_init one-hot at s=0, SW=1); parity0 = 0
  for (size_t x = t0; x < (size_t)NB * NI; x += gs) {
    const int b = (int)(x / NI), i = (int)(x % NI);
    ws[OFF_PU + x] = 0.f;
    ws[OFF_PU + (size_t)NB * NI + b * NI + i] = enc[(size_t)b * NS * NI + i];
  }
  // h fp32 + bf16 zeros (both parities)
  for (size_t x = t0; x < (size_t)2 * NC * NB; x += gs) ws[OFF_H + x] = 0.f;
  for (size_t x = t0; x < (size_t)NB * NC; x += gs) ws[OFF_H16 + x] = 0.f;  // 2 u16 parities
  // e parity1 = 1 (SE=256); w parity1 = one-hot (SW=1)
  for (size_t x = t0; x < (size_t)NB * NS; x += gs) {
    ws[OFF_E + x] = 0.f;
    ws[OFF_E + (size_t)NB * NS + x] = 1.f;
    ws[OFF_W + x] = 0.f;
    ws[OFF_W + (size_t)NB * NS + x] = ((x & (NS - 1)) == 0) ? 1.f : 0.f;
  }
  for (size_t x = t0; x < (size_t)NB; x += gs) {
    ws[OFF_SE + x] = 0.f; ws[OFF_SE + NB + x] = (float)NS;
    ws[OFF_SW + x] = 0.f; ws[OFF_SW + NB + x] = 1.f;
    ws[OFF_TRED + x] = 0.f;
  }
  unsigned* bar = (unsigned*)(ws + OFF_BAR);
  for (size_t x = t0; x < 256; x += gs) bar[x] = 0u;
  // Q16[t][b][k] bf16
  unsigned short* Q16 = (unsigned short*)(ws + OFF_Q16);
  for (size_t x = t0; x < (size_t)NT * NB * NHq; x += gs) {
    const int k = (int)(x & (NHq - 1));
    const int b = (int)((x >> 8) & (NB - 1));
    const int t = (int)(x >> 13);
    Q16[x] = (unsigned short)f2bf(queries[((size_t)b * NT + t) * NHq + k]);
  }
  // F16[t][b][k] bf16, padded 80->128 with zeros
  unsigned short* F16 = (unsigned short*)(ws + OFF_F16);
  for (size_t x = t0; x < (size_t)NT * NB * 128; x += gs) {
    const int k = (int)(x & 127);
    const int b = (int)((x >> 7) & (NB - 1));
    const int t = (int)(x >> 12);
    F16[x] = (k < NM) ? (unsigned short)f2bf(outputs[((size_t)b * NT + t) * NM + k]) : 0;
  }
  // WQ16[jq][k] bf16 (row-major copy of w_q)
  unsigned short* WQ16 = (unsigned short*)(ws + OFF_WQ16);
  for (size_t x = t0; x < (size_t)NC2 * NC; x += gs)
    WQ16[x] = (unsigned short)f2bf(w_q[x]);
}

// ---------------------------------------------------------------------------
// keyT[b][s][c2] = enc[b,s,:] @ w_k^T + b_k
__global__ __launch_bounds__(NTHR) void k_key(const float* __restrict__ enc,
                                              const float* __restrict__ b_k,
                                              float* __restrict__ ws) {
  __shared__ float encl[4 * NI];
  const int bid = blockIdx.x, tid = threadIdx.x;
  const int b = bid >> 3, s0 = (bid & 7) * 32;
  const float* wkT = ws + OFF_WKT;
  float* keyT = ws + OFF_KEYT;
  const float bk = b_k[tid];
  for (int q = 0; q < 8; ++q) {
    const int sb = s0 + q * 4;
    for (int x = tid; x < 4 * NI; x += NTHR) {
      const int ss = x >> 9, i = x & (NI - 1);
      encl[x] = enc[((size_t)(b * NS + sb + ss)) * NI + i];
    }
    __syncthreads();
    float a0 = bk, a1 = bk, a2 = bk, a3 = bk;
    for (int i = 0; i < NI; ++i) {
      const float wv = wkT[(size_t)i * NC2 + tid];
      a0 += wv * encl[i];           a1 += wv * encl[NI + i];
      a2 += wv * encl[2 * NI + i];  a3 += wv * encl[3 * NI + i];
    }
    keyT[((size_t)(b * NS + sb + 0)) * NC2 + tid] = a0;
    keyT[((size_t)(b * NS + sb + 1)) * NC2 + tid] = a1;
    keyT[((size_t)(b * NS + sb + 2)) * NC2 + tid] = a2;
    keyT[((size_t)(b * NS + sb + 3)) * NC2 + tid] = a3;
    __syncthreads();
  }
}

// ---------------------------------------------------------------------------
__global__ __launch_bounds__(NTHR, 2) void k_main(
    const float* __restrict__ enc, const float* __restrict__ mask,
    const float* __restrict__ w_ih, const float* __restrict__ w_hh,
    const float* __restrict__ b_ih, const float* __restrict__ b_hh,
    const float* __restrict__ w_loc1, const float* __restrict__ w_loc2,
    const float* __restrict__ w_agg, const float* __restrict__ w_t1,
    const float* __restrict__ b_t1, const float* __restrict__ w_t2,
    float* ws, float* __restrict__ out) {
  const int bid = blockIdx.x, tid = threadIdx.x;
  float* const keyT = ws + OFF_KEYT;
  float* const PU = ws + OFF_PU;
  float* const HB = ws + OFF_H;
  unsigned short* const HB16 = (unsigned short*)(ws + OFF_H16);
  float* const EB = ws + OFF_E;
  float* const WBUF = ws + OFF_W;
  float* const SEB = ws + OFF_SE;
  float* const SWB = ws + OFF_SW;
  float* const TPART = ws + OFF_TPART;
  float* const TRED = ws + OFF_TRED;
  float* const QBUF = ws + OFF_QBUF;
  unsigned* const bar = (unsigned*)(ws + OFF_BAR);
  const unsigned short* const Q16 = (const unsigned short*)(ws + OFF_Q16);
  const unsigned short* const F16 = (const unsigned short*)(ws + OFF_F16);
  const unsigned short* const WQ16 = (const unsigned short*)(ws + OFF_WQ16);

  __shared__ unsigned short keyl[NC2 * KLSTRIDE];  // persistent key slice (bf16)
  __shared__ float Cred[2 * 5 * 4 * 64];           // MFMA cross-wave reduce
  __shared__ float gout2[5 * 4 * 32];              // r,z,nx,nh,tp per (c4,b)
  __shared__ float swinv_l[32];
  __shared__ float tredl[128];
  __shared__ float alignl[64];
  __shared__ float wl2[34];
  __shared__ float Epart[32 * 9];
  __shared__ float wstash[32];

  const int lane = tid & 63, wv = tid >> 6;
  const int m2 = wv >> 2, k4 = wv & 3;        // PA roles
  const int kg = lane >> 4;                   // A/B fragment k-group
  const int ab = m2 * 16 + (lane & 15);       // A batch index for this lane
  const int cs = bid * 4;                     // block's 4 GRU channels
  const int pb_b = bid >> 3, pb_s0 = (bid & 7) * 32;  // PB roles
  int ph = 0;

  // ---- one-time staging -------------------------------------------------
  // B-fragments of Wcat, persistent in VGPRs: wreg[si] for this wave's steps.
  short8 wreg[16];
  {
    const int n = lane & 15;
    const int kind = n >> 2, ch = cs + (n & 3);
#pragma unroll
    for (int si = 0; si < 16; ++si) {
      int s = (k4 == 0) ? (si < 8 ? si : (si < 15 ? 16 + si : -1))
            : (k4 == 1) ? 8 + si
            : (k4 == 2) ? (si < 15 ? 31 + si : -1)
                        : (si < 14 ? 46 + si : -1);
      short8 w = {0, 0, 0, 0, 0, 0, 0, 0};
      if (s >= 0) {
        const int k0 = s * 32 + kg * 8;
#pragma unroll
        for (int jj = 0; jj < 8; ++jj)
          w[jj] = f2bf(wcat_val(w_ih, w_hh, w_t1, kind, ch, k0 + jj));
      }
      wreg[si] = w;
    }
  }
  // location-conv weights (fused 31x512), per-thread c2 = tid
  float wc[31];
#pragma unroll
  for (int k = 0; k < 31; ++k) {
    float s = 0.f;
    for (int l = 0; l < 32; ++l) s += w_loc2[tid * 32 + l] * w_loc1[l * 31 + k];
    wc[k] = s;
  }
  const float wag = w_agg[tid];
  // key slice -> LDS bf16, layout [c2][sl] with stride 34 (conflict-free b32)
  for (int x = tid; x < NC2 * 32; x += NTHR) {
    const int sl = x & 31, c2s = x >> 5;
    keyl[c2s * KLSTRIDE + sl] =
        (unsigned short)f2bf(keyT[((size_t)(pb_b * NS + pb_s0 + sl)) * NC2 + c2s]);
  }
  __syncthreads();

  for (int j = 0; j < NT; ++j) {
    const int p = j & 1;
    const float* pu_prev = PU + (size_t)(1 - p) * NB * NI;
    float* pu_cur = PU + (size_t)p * NB * NI;
    const float* h_prev = HB + (size_t)(1 - p) * NC * NB;
    float* h_cur = HB + (size_t)p * NC * NB;
    const unsigned short* hb16_prev = HB16 + (size_t)(1 - p) * NB * NC;
    unsigned short* hb16_cur = HB16 + (size_t)p * NB * NC;
    const float* e_prev = EB + (size_t)(1 - p) * NB * NS;
    float* e_cur = EB + (size_t)p * NB * NS;
    const float* w_prev = WBUF + (size_t)(1 - p) * NB * NS;
    float* w_cur = WBUF + (size_t)p * NB * NS;
    const float* se_prev = SEB + (size_t)(1 - p) * NB;
    float* se_cur = SEB + (size_t)p * NB;
    const float* sw_prev = SWB + (size_t)(1 - p) * NB;
    float* sw_cur = SWB + (size_t)p * NB;

    // ========================== Phase A ==========================
    if (tid < 64) pu_cur[bid * 64 + tid] = 0.f;
    if (bid == 0 && tid < NB) se_cur[tid] = 0.f;
    if (bid == 1 && tid < NB) sw_cur[tid] = 0.f;
    if (tid < NB) swinv_l[tid] = 1.f / sw_prev[tid];
    __syncthreads();

    if (j >= 1 && bid < NB && tid < NS)
      out[((size_t)bid * NT + (j - 1)) * NS + tid] = w_prev[bid * NS + tid] * swinv_l[bid];

    f32x4 accA = {0.f, 0.f, 0.f, 0.f}, accB = {0.f, 0.f, 0.f, 0.f};
#define PA_STEP(SI, S, ACC)                                                   \
  {                                                                           \
    short8 afrag = load_afrag<S>(j, Q16, F16, hb16_prev, pu_prev, ab, kg);    \
    ACC = __builtin_amdgcn_mfma_f32_16x16x32_bf16(afrag, wreg[SI], ACC, 0, 0, 0); \
  }
    if (k4 == 0) {
      PA_STEP(0, 0, accA)  PA_STEP(1, 1, accA)  PA_STEP(2, 2, accA)  PA_STEP(3, 3, accA)
      PA_STEP(4, 4, accA)  PA_STEP(5, 5, accA)  PA_STEP(6, 6, accA)  PA_STEP(7, 7, accA)
      PA_STEP(8, 24, accB) PA_STEP(9, 25, accB) PA_STEP(10, 26, accB) PA_STEP(11, 27, accB)
      PA_STEP(12, 28, accB) PA_STEP(13, 29, accB) PA_STEP(14, 30, accB)
    } else if (k4 == 1) {
      PA_STEP(0, 8, accA)  PA_STEP(1, 9, accA)  PA_STEP(2, 10, accA) PA_STEP(3, 11, accA)
      PA_STEP(4, 12, accA) PA_STEP(5, 13, accA) PA_STEP(6, 14, accA) PA_STEP(7, 15, accA)
      PA_STEP(8, 16, accA) PA_STEP(9, 17, accA) PA_STEP(10, 18, accA) PA_STEP(11, 19, accA)
      PA_STEP(12, 20, accA) PA_STEP(13, 21, accA) PA_STEP(14, 22, accA) PA_STEP(15, 23, accA)
    } else if (k4 == 2) {
      PA_STEP(0, 31, accA) PA_STEP(1, 32, accA) PA_STEP(2, 33, accA) PA_STEP(3, 34, accA)
      PA_STEP(4, 35, accA) PA_STEP(5, 36, accA) PA_STEP(6, 37, accA) PA_STEP(7, 38, accA)
      PA_STEP(8, 39, accA) PA_STEP(9, 40, accA) PA_STEP(10, 41, accA) PA_STEP(11, 42, accA)
      PA_STEP(12, 43, accA) PA_STEP(13, 44, accA) PA_STEP(14, 45, accA)
    } else {
      PA_STEP(0, 46, accA) PA_STEP(1, 47, accA) PA_STEP(2, 48, accA) PA_STEP(3, 49, accA)
      PA_STEP(4, 50, accA) PA_STEP(5, 51, accA) PA_STEP(6, 52, accA) PA_STEP(7, 53, accA)
      PA_STEP(8, 54, accA) PA_STEP(9, 55, accA) PA_STEP(10, 56, accA) PA_STEP(11, 57, accA)
      PA_STEP(12, 58, accA) PA_STEP(13, 59, accA)
    }
#undef PA_STEP
    // Cred[m2][sg][r][lane]: sg 0=w0.A(q) 1=w0.B(h-part) 2=w1.A(prev) 3=w2.A 4=w3.A
    {
      auto cidx = [](int m, int sg, int r, int l) { return ((m * 5 + sg) * 4 + r) * 64 + l; };
      if (k4 == 0) {
#pragma unroll
        for (int r = 0; r < 4; ++r) {
          Cred[cidx(m2, 0, r, lane)] = accA[r];
          Cred[cidx(m2, 1, r, lane)] = accB[r];
        }
      } else {
        const int sg = 1 + k4;
#pragma unroll
        for (int r = 0; r < 4; ++r) Cred[cidx(m2, sg, r, lane)] = accA[r];
      }
    }
    __syncthreads();
    {  // combine: gate = s0 + swinv*s1 + s2  (n-gate keeps x/h split)
      const int n = tid & 15, b = tid >> 4;
      const int m2r = b >> 4, bm = b & 15, l = (bm >> 2) * 16 + n, r = bm & 3;
      auto cidx = [](int m, int sg, int rr, int ll) { return ((m * 5 + sg) * 4 + rr) * 64 + ll; };
      const float s0 = Cred[cidx(m2r, 0, r, l)];
      const float sB = Cred[cidx(m2r, 1, r, l)];
      const float s1 = Cred[cidx(m2r, 2, r, l)];
      const float s2 = sB + Cred[cidx(m2r, 3, r, l)] + Cred[cidx(m2r, 4, r, l)];
      const float swv = swinv_l[b];
      const int kind = n >> 2, c4o = n & 3;
      if (kind == 2) {
        gout2[2 * 128 + c4o * 32 + b] = s0 + swv * s1;
        gout2[3 * 128 + c4o * 32 + b] = s2;
      } else {
        const int slot = (kind == 3) ? 4 : kind;
        gout2[slot * 128 + c4o * 32 + b] = s0 + swv * s1 + s2;
      }
    }
    __syncthreads();
    if (tid < 128) {  // GRU update, 4 channels x 32 batches
      const int c4o = tid >> 5, b = tid & 31, c = cs + c4o;
      const float xr = gout2[0 * 128 + c4o * 32 + b] + b_ih[c] + b_hh[c];
      const float xz = gout2[1 * 128 + c4o * 32 + b] + b_ih[NC + c] + b_hh[NC + c];
      const float xn = gout2[2 * 128 + c4o * 32 + b] + b_ih[2 * NC + c];
      const float hn = gout2[3 * 128 + c4o * 32 + b] + b_hh[2 * NC + c];
      const float tp = gout2[4 * 128 + c4o * 32 + b];
      const float r = fsig(xr), z = fsig(xz);
      const float nn = ftanh(xn + r * hn);
      const float hnew = (1.f - z) * nn + z * h_prev[c * 32 + b];
      h_cur[c * 32 + b] = hnew;
      hb16_cur[(size_t)b * NC + c] = (unsigned short)f2bf(hnew);
      tredl[c4o * 32 + b] = w_t2[c] * ftanh(tp + b_t1[c]);
    }
    __syncthreads();
    if (tid < NB)
      TPART[bid * NB + tid] = tredl[tid] + tredl[32 + tid] + tredl[64 + tid] + tredl[96 + tid];
    gbarrier(bar, ph);

    // ========================== Phase Q ==========================
    if (bid < 32) {  // q = h_new @ w_q^T via MFMA; block owns 16 q-cols
      f32x4 qacc = {0.f, 0.f, 0.f, 0.f};
      const unsigned short* hb = HB16 + (size_t)p * NB * NC;
      const int col = lane & 15;
      const int jq = bid * 16 + col;
      for (int ks = 0; ks < 8; ++ks) {
        const int s = k4 * 8 + ks;
        const short8 a = *(const short8*)(hb + (size_t)ab * NC + s * 32 + kg * 8);
        const short8 bf = *(const short8*)(WQ16 + (size_t)jq * NC + s * 32 + kg * 8);
        qacc = __builtin_amdgcn_mfma_f32_16x16x32_bf16(a, bf, qacc, 0, 0, 0);
      }
#pragma unroll
      for (int r = 0; r < 4; ++r) Cred[((m2 * 4 + k4) * 4 + r) * 64 + lane] = qacc[r];
      __syncthreads();
      {
        const int col2 = tid & 15, b2 = tid >> 4;
        const int m2r = b2 >> 4, bm = b2 & 15, l = (bm >> 2) * 16 + col2, r = bm & 3;
        float s = 0.f;
#pragma unroll
        for (int kk = 0; kk < 4; ++kk) s += Cred[((m2r * 4 + kk) * 4 + r) * 64 + l];
        QBUF[(size_t)b2 * NC2 + bid * 16 + col2] = s;
      }
    } else if (bid >= 64 && bid < 96) {  // trans reduce for batch b = bid-64
      const int b2 = bid - 64;
      float v = (tid < NBLK) ? TPART[tid * NB + b2] : 0.f;
#pragma unroll
      for (int off = 32; off > 0; off >>= 1) v += __shfl_down(v, off);
      if (lane == 0) Cred[wv] = v;
      __syncthreads();
      if (tid == 0) {
        float s = 0.f;
#pragma unroll
        for (int w8 = 0; w8 < 8; ++w8) s += Cred[w8];
        TRED[b2] = s;
      }
    }
    gbarrier(bar, ph);

    // ========================== Phase B ==========================
    {
      const int b = pb_b, s0 = pb_s0;
      const float invSE = 1.f / se_prev[b];
      const float invSW = 1.f / sw_prev[b];
      const float tr = (j == 0) ? 0.5f : fsig(TRED[b]);
      if (tid < 62) {  // align window (zero-padded conv halo)
        const int sp = s0 + tid - 15;
        alignl[tid] = (sp >= 0 && sp < NS) ? e_prev[b * NS + sp] * invSE : 0.f;
      }
      if (tid >= 64 && tid < 97) {  // alpha_{j-1} halo for the shift term
        const int i2 = tid - 64, sp = s0 + i2 - 1;
        wl2[i2] = (sp >= 0 && sp < NS) ? w_prev[b * NS + sp] * invSW : 0.f;
      }
      __syncthreads();
      const int wvx = wv;
      const float qv = QBUF[(size_t)b * NC2 + tid];
      float al[62];
#pragma unroll
      for (int x = 0; x < 62; ++x) al[x] = alignl[x];
      const unsigned* kp = (const unsigned*)&keyl[tid * KLSTRIDE];  // 4B-aligned (68B stride)
#pragma unroll
      for (int sl8 = 0; sl8 < 4; ++sl8) {
#pragma unroll
        for (int i2 = 0; i2 < 4; ++i2) {
          const unsigned kw = kp[sl8 * 4 + i2];
#pragma unroll
          for (int hh = 0; hh < 2; ++hh) {
            const int sl = sl8 * 8 + i2 * 2 + hh;
            const float kv = bf2f((short)(hh ? (kw >> 16) : (kw & 0xffffu)));
            float conv = 0.f;
#pragma unroll
            for (int k = 0; k < 31; ++k) conv += wc[k] * al[sl + k];
            float pe = wag * ftanh(conv + qv + kv);
#pragma unroll
            for (int off = 32; off > 0; off >>= 1) pe += __shfl_down(pe, off);
            if (lane == 0) Epart[sl * 9 + wvx] = pe;
          }
        }
      }
      __syncthreads();
      if (tid < 32) {  // finalize energies for this block's 32 s-positions
        const int sl = tid, s = s0 + sl;
        float Ev = 0.f;
#pragma unroll
        for (int w8 = 0; w8 < 8; ++w8) Ev += Epart[sl * 9 + w8];
        const float ev = (mask[b * NS + s] != 0.f) ? __expf(Ev) : 0.f;
        const float csv = (1.f - tr) * wl2[sl + 1] + tr * wl2[sl] + 1e-7f;
        const float wvv = csv * ev;
        e_cur[b * NS + s] = ev;
        w_cur[b * NS + s] = wvv;
        wstash[sl] = wvv;
        float se = ev, sw2 = wvv;
#pragma unroll
        for (int off = 16; off > 0; off >>= 1) {
          se += __shfl_down(se, off, 32);
          sw2 += __shfl_down(sw2, off, 32);
        }
        if (sl == 0) { atomicAdd(&se_cur[b], se); atomicAdd(&sw_cur[b], sw2); }
      }
      __syncthreads();
      {  // prevU[b][i] += sum_s w_s * enc[b,s,i]
        float acc = 0.f;
        const float* encb = enc + ((size_t)(b * NS + s0)) * NI + tid;
#pragma unroll 8
        for (int ss = 0; ss < 32; ++ss) acc += wstash[ss] * encb[(size_t)ss * NI];
        atomicAdd(&pu_cur[(size_t)b * NI + tid], acc);
      }
    }
    gbarrier(bar, ph);
  }

  // epilogue: alpha_{T-1} (parity 1 since 799 is odd)
  if (bid < NB && tid < NS) {
    const float invSW = 1.f / SWB[NB + bid];
    out[((size_t)bid * NT + (NT - 1)) * NS + tid] =
        WBUF[(size_t)NB * NS + bid * NS + tid] * invSW;
  }
}

// ---------------------------------------------------------------------------
extern "C" void kernel_launch(void* const* d_in, const int* in_sizes, int n_in,
                              void* d_out, int out_size, void* d_ws, size_t ws_size,
                              hipStream_t stream) {
  const float* enc     = (const float*)d_in[0];
  const float* queries = (const float*)d_in[1];
  const float* outputs = (const float*)d_in[2];
  const float* mask    = (const float*)d_in[3];
  const float* w_ih    = (const float*)d_in[4];
  const float* w_hh    = (const float*)d_in[5];
  const float* b_ih    = (const float*)d_in[6];
  const float* b_hh    = (const float*)d_in[7];
  const float* w_q     = (const float*)d_in[8];
  const float* w_loc1  = (const float*)d_in[9];
  const float* w_loc2  = (const float*)d_in[10];
  const float* w_k     = (const float*)d_in[11];
  const float* b_k     = (const float*)d_in[12];
  const float* w_agg   = (const float*)d_in[13];
  const float* w_t1    = (const float*)d_in[14];
  const float* b_t1    = (const float*)d_in[15];
  const float* w_t2    = (const float*)d_in[16];
  float* ws = (float*)d_ws;
  float* out = (float*)d_out;
  (void)in_sizes; (void)n_in; (void)out_size; (void)ws_size;

  k_init<<<dim3(1024), dim3(256), 0, stream>>>(enc, queries, outputs, w_k, w_q, ws);
  k_key<<<dim3(NBLK), dim3(NTHR), 0, stream>>>(enc, b_k, ws);
  k_main<<<dim3(NBLK), dim3(NTHR), 0, stream>>>(enc, mask, w_ih, w_hh, b_ih, b_hh,
                                                w_loc1, w_loc2, w_agg, w_t1,
                                                b_t1, w_t2, ws, out);
}

// Round 5
// 25546.701 us; speedup vs baseline: 6.6331x; 1.7719x over previous
//
#include <hip/hip_runtime.h>
#include <cstdint>
#include <cstddef>

// ============================================================================
// Aligner (forward attention + GRU), persistent-kernel, MFMA-bf16 edition.
// Round 5: NO cache-maintenance fences. Cross-block state goes through
// agent-coherent (sc0 sc1) loads/stores that bypass L1/L2 to the coherence
// point; read-only data stays L2-cached across steps. Device barrier is a
// contention-free flag barrier (per-block flag lines + master aggregate +
// root broadcast). Bulk MFMA fragments use grouped inline-asm sc1 loads with
// a single vmcnt(0) per group (volatile would serialize per-load).
// ============================================================================

namespace cfg {
constexpr int NB = 32, NS = 256, NI = 512, NHq = 256, NM = 80;
constexpr int NC = 1024, NC2 = 512, NT = 800;
constexpr int NBLK = 256, NTHR = 512;

constexpr size_t OFF_KEYT  = 0;                                   // 32*256*512 f32
constexpr size_t OFF_WKT   = OFF_KEYT + (size_t)NB * NS * NC2;    // 512*512 f32
constexpr size_t OFF_PU    = OFF_WKT + (size_t)NI * NC2;          // 2*32*512 f32 [b][i]
constexpr size_t OFF_H     = OFF_PU + (size_t)2 * NB * NI;        // 2*1024*32 f32 [c][b]
constexpr size_t OFF_H16   = OFF_H + (size_t)2 * NC * NB;         // 2*32*1024 u16 [b][c]
constexpr size_t OFF_E     = OFF_H16 + (size_t)NB * NC;           // 2*32*256 f32
constexpr size_t OFF_W     = OFF_E + (size_t)2 * NB * NS;         // 2*32*256 f32
constexpr size_t OFF_SE    = OFF_W + (size_t)2 * NB * NS;         // 64
constexpr size_t OFF_SW    = OFF_SE + 64;                         // 64
constexpr size_t OFF_TPART = OFF_SW + 64;                         // 256*32
constexpr size_t OFF_TRED  = OFF_TPART + (size_t)NBLK * NB;       // 32
constexpr size_t OFF_QBUF  = OFF_TRED + 32;                       // 32*512
constexpr size_t OFF_BAR   = OFF_QBUF + (size_t)NB * NC2;         // 4608 uints: root + 256 flag lines
constexpr size_t OFF_Q16   = OFF_BAR + 4608;                      // 800*32*256 u16
constexpr size_t OFF_F16   = OFF_Q16 + (size_t)NT * NB * NHq / 2; // 800*32*128 u16
constexpr size_t OFF_WQ16  = OFF_F16 + (size_t)NT * NB * 128 / 2; // 512*1024 u16
constexpr size_t WS_FLOATS = OFF_WQ16 + (size_t)NC2 * NC / 2;
constexpr int KLSTRIDE = 34;  // keyl leading stride in shorts (word stride 17, odd)
}
using namespace cfg;

typedef __attribute__((ext_vector_type(8))) short short8;
typedef __attribute__((ext_vector_type(4))) float f32x4;

#define MF(a, b, c) __builtin_amdgcn_mfma_f32_16x16x32_bf16((a), (b), (c), 0, 0, 0)
// coherent (agent-scope, L1/L2-bypassing) 16B load, NO wait — group + vw*()
#define LDSC(d, p) asm volatile("global_load_dwordx4 %0, %1, off sc0 sc1" : "=v"(d) : "v"(p))

__device__ __forceinline__ float ld_cg(const float* p) {
  return __hip_atomic_load(p, __ATOMIC_RELAXED, __HIP_MEMORY_SCOPE_AGENT);
}
__device__ __forceinline__ void st_cg(float* p, float v) {
  __hip_atomic_store(p, v, __ATOMIC_RELAXED, __HIP_MEMORY_SCOPE_AGENT);
}
__device__ __forceinline__ void st_cg_u16(unsigned short* p, unsigned short v) {
  asm volatile("global_store_short %0, %1, off sc0 sc1" :: "v"(p), "v"((unsigned)v) : "memory");
}

__device__ __forceinline__ void vw7(short8& a0, short8& a1, short8& a2, short8& a3,
                                    short8& a4, short8& a5, short8& a6) {
  asm volatile("s_waitcnt vmcnt(0)"
               : "+v"(a0), "+v"(a1), "+v"(a2), "+v"(a3), "+v"(a4), "+v"(a5), "+v"(a6));
}
__device__ __forceinline__ void vw8(short8& a0, short8& a1, short8& a2, short8& a3,
                                    short8& a4, short8& a5, short8& a6, short8& a7) {
  asm volatile("s_waitcnt vmcnt(0)"
               : "+v"(a0), "+v"(a1), "+v"(a2), "+v"(a3), "+v"(a4), "+v"(a5), "+v"(a6), "+v"(a7));
}
__device__ __forceinline__ void vw10(short8& a0, short8& a1, short8& a2, short8& a3, short8& a4,
                                     short8& a5, short8& a6, short8& a7, short8& a8, short8& a9) {
  asm volatile("s_waitcnt vmcnt(0)"
               : "+v"(a0), "+v"(a1), "+v"(a2), "+v"(a3), "+v"(a4), "+v"(a5), "+v"(a6),
                 "+v"(a7), "+v"(a8), "+v"(a9));
}
__device__ __forceinline__ void vw15(short8& a0, short8& a1, short8& a2, short8& a3, short8& a4,
                                     short8& a5, short8& a6, short8& a7, short8& a8, short8& a9,
                                     short8& aa, short8& ab2, short8& ac, short8& ad, short8& ae) {
  asm volatile("s_waitcnt vmcnt(0)"
               : "+v"(a0), "+v"(a1), "+v"(a2), "+v"(a3), "+v"(a4), "+v"(a5), "+v"(a6),
                 "+v"(a7), "+v"(a8), "+v"(a9), "+v"(aa), "+v"(ab2), "+v"(ac), "+v"(ad), "+v"(ae));
}
__device__ __forceinline__ void vw16f(f32x4& a0, f32x4& a1, f32x4& a2, f32x4& a3, f32x4& a4,
                                      f32x4& a5, f32x4& a6, f32x4& a7, f32x4& b0, f32x4& b1,
                                      f32x4& b2, f32x4& b3, f32x4& b4, f32x4& b5, f32x4& b6,
                                      f32x4& b7) {
  asm volatile("s_waitcnt vmcnt(0)"
               : "+v"(a0), "+v"(a1), "+v"(a2), "+v"(a3), "+v"(a4), "+v"(a5), "+v"(a6), "+v"(a7),
                 "+v"(b0), "+v"(b1), "+v"(b2), "+v"(b3), "+v"(b4), "+v"(b5), "+v"(b6), "+v"(b7));
}

__device__ __forceinline__ float frcp(float x) {
#if __has_builtin(__builtin_amdgcn_rcpf)
  return __builtin_amdgcn_rcpf(x);
#else
  return 1.f / x;
#endif
}
__device__ __forceinline__ float fsig(float x) { return frcp(1.f + __expf(-x)); }
__device__ __forceinline__ float ftanh(float x) {
  const float e = __expf(2.f * x);
  return 1.f - 2.f * frcp(e + 1.f);
}
__device__ __forceinline__ short f2bf(float f) {  // RNE f32 -> bf16 bits
  unsigned u = __float_as_uint(f);
  u += 0x7FFFu + ((u >> 16) & 1u);
  return (short)(u >> 16);
}
__device__ __forceinline__ float bf2f(short s) {
  return __uint_as_float(((unsigned)(unsigned short)s) << 16);
}
__device__ __forceinline__ short8 cvt8(f32x4 lo, f32x4 hi) {
  short8 a;
  a[0] = f2bf(lo[0]); a[1] = f2bf(lo[1]); a[2] = f2bf(lo[2]); a[3] = f2bf(lo[3]);
  a[4] = f2bf(hi[0]); a[5] = f2bf(hi[1]); a[6] = f2bf(hi[2]); a[7] = f2bf(hi[3]);
  return a;
}

// Flag barrier: no cache-maintenance fences; visibility comes from all shared
// data being written with sc0|sc1 (coherent) and drained via vmcnt(0) before
// arrival. Per-block flag lines (64B apart) kill same-address atomic
// contention; block 0 aggregates with 255 parallel pollers.
__device__ __forceinline__ void gbarrier(unsigned* root, unsigned* flags, unsigned& ph) {
  ++ph;
  asm volatile("s_waitcnt vmcnt(0)" ::: "memory");  // drain sc1 stores + atomics
  __syncthreads();
  if (blockIdx.x == 0) {
    const int t = threadIdx.x;
    if (t > 0 && t < 256) {
      while (__hip_atomic_load(&flags[t * 16], __ATOMIC_RELAXED, __HIP_MEMORY_SCOPE_AGENT) < ph)
        __builtin_amdgcn_s_sleep(1);
    }
    __syncthreads();
    if (t == 0)
      __hip_atomic_store(root, ph, __ATOMIC_RELAXED, __HIP_MEMORY_SCOPE_AGENT);
  } else {
    if (threadIdx.x == 0) {
      __hip_atomic_store(&flags[blockIdx.x * 16], ph, __ATOMIC_RELAXED, __HIP_MEMORY_SCOPE_AGENT);
      while (__hip_atomic_load(root, __ATOMIC_RELAXED, __HIP_MEMORY_SCOPE_AGENT) < ph)
        __builtin_amdgcn_s_sleep(1);
    }
  }
  __syncthreads();
}

// Wcat element (kind: 0=r,1=z,2=n,3=tp; c: channel; k: 0..1919)
__device__ __forceinline__ float wcat_val(const float* __restrict__ w_ih,
                                          const float* __restrict__ w_hh,
                                          const float* __restrict__ w_t1,
                                          int kind, int c, int k) {
  if (kind < 3) {
    const int gr = kind * NC + c;
    if (k < 768) return w_ih[(size_t)gr * 768 + k];
    if (k < 1792) return w_hh[(size_t)gr * NC + (k - 768)];
    return 0.f;
  }
  if (k >= 256 && k < 768) return w_t1[(size_t)c * 1616 + (k - 256)];
  if (k >= 768 && k < 1792) return w_t1[(size_t)c * 1616 + 592 + (k - 768)];
  if (k >= 1792 && k < 1872) return w_t1[(size_t)c * 1616 + 512 + (k - 1792)];
  return 0.f;
}

// ---------------------------------------------------------------------------
__global__ void k_init(const float* __restrict__ enc, const float* __restrict__ queries,
                       const float* __restrict__ outputs, const float* __restrict__ w_k,
                       const float* __restrict__ w_q, float* __restrict__ ws) {
  const size_t t0 = (size_t)blockIdx.x * blockDim.x + threadIdx.x;
  const size_t gs = (size_t)gridDim.x * blockDim.x;
  for (size_t x = t0; x < (size_t)NI * NC2; x += gs) {
    const int i = (int)(x / NC2), c2 = (int)(x % NC2);
    ws[OFF_WKT + x] = w_k[(size_t)c2 * NI + i];
  }
  // PU parity1 = enc[b,0,:]  (alpha_init one-hot at s=0, SW=1); parity0 = 0
  for (size_t x = t0; x < (size_t)NB * NI; x += gs) {
    const int b = (int)(x / NI), i = (int)(x % NI);
    ws[OFF_PU + x] = 0.f;
    ws[OFF_PU + (size_t)NB * NI + b * NI + i] = enc[(size_t)b * NS * NI + i];
  }
  for (size_t x = t0; x < (size_t)2 * NC * NB; x += gs) ws[OFF_H + x] = 0.f;
  for (size_t x = t0; x < (size_t)NB * NC; x += gs) ws[OFF_H16 + x] = 0.f;  // 2 u16 parities
  // e parity1 = 1 (SE=256); w parity1 = one-hot (SW=1)
  for (size_t x = t0; x < (size_t)NB * NS; x += gs) {
    ws[OFF_E + x] = 0.f;
    ws[OFF_E + (size_t)NB * NS + x] = 1.f;
    ws[OFF_W + x] = 0.f;
    ws[OFF_W + (size_t)NB * NS + x] = ((x & (NS - 1)) == 0) ? 1.f : 0.f;
  }
  for (size_t x = t0; x < (size_t)NB; x += gs) {
    ws[OFF_SE + x] = 0.f; ws[OFF_SE + NB + x] = (float)NS;
    ws[OFF_SW + x] = 0.f; ws[OFF_SW + NB + x] = 1.f;
    ws[OFF_TRED + x] = 0.f;
  }
  unsigned* bar = (unsigned*)(ws + OFF_BAR);
  for (size_t x = t0; x < 4608; x += gs) bar[x] = 0u;
  unsigned short* Q16 = (unsigned short*)(ws + OFF_Q16);
  for (size_t x = t0; x < (size_t)NT * NB * NHq; x += gs) {
    const int k = (int)(x & (NHq - 1));
    const int b = (int)((x >> 8) & (NB - 1));
    const int t = (int)(x >> 13);
    Q16[x] = (unsigned short)f2bf(queries[((size_t)b * NT + t) * NHq + k]);
  }
  unsigned short* F16 = (unsigned short*)(ws + OFF_F16);
  for (size_t x = t0; x < (size_t)NT * NB * 128; x += gs) {
    const int k = (int)(x & 127);
    const int b = (int)((x >> 7) & (NB - 1));
    const int t = (int)(x >> 12);
    F16[x] = (k < NM) ? (unsigned short)f2bf(outputs[((size_t)b * NT + t) * NM + k]) : 0;
  }
  unsigned short* WQ16 = (unsigned short*)(ws + OFF_WQ16);
  for (size_t x = t0; x < (size_t)NC2 * NC; x += gs)
    WQ16[x] = (unsigned short)f2bf(w_q[x]);
}

// ---------------------------------------------------------------------------
// keyT[b][s][c2] = enc[b,s,:] @ w_k^T + b_k
__global__ __launch_bounds__(NTHR) void k_key(const float* __restrict__ enc,
                                              const float* __restrict__ b_k,
                                              float* __restrict__ ws) {
  __shared__ float encl[4 * NI];
  const int bid = blockIdx.x, tid = threadIdx.x;
  const int b = bid >> 3, s0 = (bid & 7) * 32;
  const float* wkT = ws + OFF_WKT;
  float* keyT = ws + OFF_KEYT;
  const float bk = b_k[tid];
  for (int q = 0; q < 8; ++q) {
    const int sb = s0 + q * 4;
    for (int x = tid; x < 4 * NI; x += NTHR) {
      const int ss = x >> 9, i = x & (NI - 1);
      encl[x] = enc[((size_t)(b * NS + sb + ss)) * NI + i];
    }
    __syncthreads();
    float a0 = bk, a1 = bk, a2 = bk, a3 = bk;
    for (int i = 0; i < NI; ++i) {
      const float wv = wkT[(size_t)i * NC2 + tid];
      a0 += wv * encl[i];           a1 += wv * encl[NI + i];
      a2 += wv * encl[2 * NI + i];  a3 += wv * encl[3 * NI + i];
    }
    keyT[((size_t)(b * NS + sb + 0)) * NC2 + tid] = a0;
    keyT[((size_t)(b * NS + sb + 1)) * NC2 + tid] = a1;
    keyT[((size_t)(b * NS + sb + 2)) * NC2 + tid] = a2;
    keyT[((size_t)(b * NS + sb + 3)) * NC2 + tid] = a3;
    __syncthreads();
  }
}

// ---------------------------------------------------------------------------
__global__ __launch_bounds__(NTHR, 2) void k_main(
    const float* __restrict__ enc, const float* __restrict__ mask,
    const float* __restrict__ w_ih, const float* __restrict__ w_hh,
    const float* __restrict__ b_ih, const float* __restrict__ b_hh,
    const float* __restrict__ w_loc1, const float* __restrict__ w_loc2,
    const float* __restrict__ w_agg, const float* __restrict__ w_t1,
    const float* __restrict__ b_t1, const float* __restrict__ w_t2,
    float* ws, float* __restrict__ out) {
  const int bid = blockIdx.x, tid = threadIdx.x;
  float* const keyT = ws + OFF_KEYT;
  float* const PU = ws + OFF_PU;
  float* const HB = ws + OFF_H;
  unsigned short* const HB16 = (unsigned short*)(ws + OFF_H16);
  float* const EB = ws + OFF_E;
  float* const WBUF = ws + OFF_W;
  float* const SEB = ws + OFF_SE;
  float* const SWB = ws + OFF_SW;
  float* const TPART = ws + OFF_TPART;
  float* const TRED = ws + OFF_TRED;
  float* const QBUF = ws + OFF_QBUF;
  unsigned* const root = (unsigned*)(ws + OFF_BAR);
  unsigned* const flags = root + 16;
  const unsigned short* const Q16 = (const unsigned short*)(ws + OFF_Q16);
  const unsigned short* const F16 = (const unsigned short*)(ws + OFF_F16);
  const unsigned short* const WQ16 = (const unsigned short*)(ws + OFF_WQ16);

  __shared__ unsigned short keyl[NC2 * KLSTRIDE];  // persistent key slice (bf16)
  __shared__ float Cred[2 * 5 * 4 * 64];           // MFMA cross-wave reduce
  __shared__ float gout2[5 * 4 * 32];              // r,z,nx,nh,tp per (c4,b)
  __shared__ float swinv_l[32];
  __shared__ float tredl[128];
  __shared__ float alignl[64];
  __shared__ float wl2[34];
  __shared__ float Epart[32 * 9];
  __shared__ float wstash[32];
  __shared__ float scal[4];  // sel, swl, trl

  const int lane = tid & 63, wv = tid >> 6;
  const int m2 = wv >> 2, k4 = wv & 3;        // PA roles
  const int kg = lane >> 4;                   // A/B fragment k-group
  const int ab = m2 * 16 + (lane & 15);       // A batch index for this lane
  const int cs = bid * 4;                     // block's 4 GRU channels
  const int pb_b = bid >> 3, pb_s0 = (bid & 7) * 32;  // PB roles
  unsigned ph = 0;

  // ---- one-time staging -------------------------------------------------
  short8 wreg[16];
  {
    const int n = lane & 15;
    const int kind = n >> 2, ch = cs + (n & 3);
#pragma unroll
    for (int si = 0; si < 16; ++si) {
      int s = (k4 == 0) ? (si < 8 ? si : (si < 15 ? 16 + si : -1))
            : (k4 == 1) ? 8 + si
            : (k4 == 2) ? (si < 15 ? 31 + si : -1)
                        : (si < 14 ? 46 + si : -1);
      short8 w = {0, 0, 0, 0, 0, 0, 0, 0};
      if (s >= 0) {
        const int k0 = s * 32 + kg * 8;
#pragma unroll
        for (int jj = 0; jj < 8; ++jj)
          w[jj] = f2bf(wcat_val(w_ih, w_hh, w_t1, kind, ch, k0 + jj));
      }
      wreg[si] = w;
    }
  }
  float wc[31];
#pragma unroll
  for (int k = 0; k < 31; ++k) {
    float s = 0.f;
    for (int l = 0; l < 32; ++l) s += w_loc2[tid * 32 + l] * w_loc1[l * 31 + k];
    wc[k] = s;
  }
  const float wag = w_agg[tid];
  for (int x = tid; x < NC2 * 32; x += NTHR) {
    const int sl = x & 31, c2s = x >> 5;
    keyl[c2s * KLSTRIDE + sl] =
        (unsigned short)f2bf(keyT[((size_t)(pb_b * NS + pb_s0 + sl)) * NC2 + c2s]);
  }
  __syncthreads();

  for (int j = 0; j < NT; ++j) {
    const int p = j & 1;
    const float* pu_prev = PU + (size_t)(1 - p) * NB * NI;
    float* pu_cur = PU + (size_t)p * NB * NI;
    const float* h_prev = HB + (size_t)(1 - p) * NC * NB;
    float* h_cur = HB + (size_t)p * NC * NB;
    const unsigned short* hb16_prev = HB16 + (size_t)(1 - p) * NB * NC;
    unsigned short* hb16_cur = HB16 + (size_t)p * NB * NC;
    const float* e_prev = EB + (size_t)(1 - p) * NB * NS;
    float* e_cur = EB + (size_t)p * NB * NS;
    const float* w_prev = WBUF + (size_t)(1 - p) * NB * NS;
    float* w_cur = WBUF + (size_t)p * NB * NS;
    const float* se_prev = SEB + (size_t)(1 - p) * NB;
    float* se_cur = SEB + (size_t)p * NB;
    const float* sw_prev = SWB + (size_t)(1 - p) * NB;
    float* sw_cur = SWB + (size_t)p * NB;

    // ========================== Phase A ==========================
    if (tid < 64) st_cg(&pu_cur[bid * 64 + tid], 0.f);
    if (bid == 0 && tid < NB) st_cg(&se_cur[tid], 0.f);
    if (bid == 1 && tid < NB) st_cg(&sw_cur[tid], 0.f);
    if (tid < NB) swinv_l[tid] = 1.f / ld_cg(&sw_prev[tid]);
    __syncthreads();

    if (j >= 1 && bid < NB && tid < NS)
      out[((size_t)bid * NT + (j - 1)) * NS + tid] = ld_cg(&w_prev[bid * NS + tid]) * swinv_l[bid];

    f32x4 accA = {0.f, 0.f, 0.f, 0.f}, accB = {0.f, 0.f, 0.f, 0.f};
    if (k4 == 0) {
      const unsigned short* qp = Q16 + ((size_t)j * NB + ab) * NHq + kg * 8;
      const unsigned short* hp = hb16_prev + (size_t)ab * NC + kg * 8;
      short8 h0, h1, h2, h3, h4, h5, h6;
      LDSC(h0, hp);        LDSC(h1, hp + 32);   LDSC(h2, hp + 64);  LDSC(h3, hp + 96);
      LDSC(h4, hp + 128);  LDSC(h5, hp + 160);  LDSC(h6, hp + 192);
      const short8 q0 = *(const short8*)(qp);
      const short8 q1 = *(const short8*)(qp + 32);
      const short8 q2 = *(const short8*)(qp + 64);
      const short8 q3 = *(const short8*)(qp + 96);
      const short8 q4 = *(const short8*)(qp + 128);
      const short8 q5 = *(const short8*)(qp + 160);
      const short8 q6 = *(const short8*)(qp + 192);
      const short8 q7 = *(const short8*)(qp + 224);
      vw7(h0, h1, h2, h3, h4, h5, h6);
      accA = MF(q0, wreg[0], accA); accA = MF(q1, wreg[1], accA);
      accA = MF(q2, wreg[2], accA); accA = MF(q3, wreg[3], accA);
      accA = MF(q4, wreg[4], accA); accA = MF(q5, wreg[5], accA);
      accA = MF(q6, wreg[6], accA); accA = MF(q7, wreg[7], accA);
      accB = MF(h0, wreg[8], accB);  accB = MF(h1, wreg[9], accB);
      accB = MF(h2, wreg[10], accB); accB = MF(h3, wreg[11], accB);
      accB = MF(h4, wreg[12], accB); accB = MF(h5, wreg[13], accB);
      accB = MF(h6, wreg[14], accB);
    } else if (k4 == 1) {
      const float* pp = pu_prev + (size_t)ab * NI + kg * 8;
#pragma unroll
      for (int rd = 0; rd < 2; ++rd) {
        const float* pb = pp + rd * 256;
        f32x4 a0, a1, a2, a3, a4, a5, a6, a7, b0, b1, b2, b3, b4, b5, b6, b7;
        LDSC(a0, pb);        LDSC(b0, pb + 4);
        LDSC(a1, pb + 32);   LDSC(b1, pb + 36);
        LDSC(a2, pb + 64);   LDSC(b2, pb + 68);
        LDSC(a3, pb + 96);   LDSC(b3, pb + 100);
        LDSC(a4, pb + 128);  LDSC(b4, pb + 132);
        LDSC(a5, pb + 160);  LDSC(b5, pb + 164);
        LDSC(a6, pb + 192);  LDSC(b6, pb + 196);
        LDSC(a7, pb + 224);  LDSC(b7, pb + 228);
        vw16f(a0, a1, a2, a3, a4, a5, a6, a7, b0, b1, b2, b3, b4, b5, b6, b7);
        const int w0 = rd * 8;
        accA = MF(cvt8(a0, b0), wreg[w0 + 0], accA);
        accA = MF(cvt8(a1, b1), wreg[w0 + 1], accA);
        accA = MF(cvt8(a2, b2), wreg[w0 + 2], accA);
        accA = MF(cvt8(a3, b3), wreg[w0 + 3], accA);
        accA = MF(cvt8(a4, b4), wreg[w0 + 4], accA);
        accA = MF(cvt8(a5, b5), wreg[w0 + 5], accA);
        accA = MF(cvt8(a6, b6), wreg[w0 + 6], accA);
        accA = MF(cvt8(a7, b7), wreg[w0 + 7], accA);
      }
    } else if (k4 == 2) {
      const unsigned short* hp = hb16_prev + (size_t)ab * NC + kg * 8 + 224;
      short8 h0, h1, h2, h3, h4, h5, h6, h7, h8, h9, ha, hb2, hc, hd, he;
      LDSC(h0, hp);        LDSC(h1, hp + 32);  LDSC(h2, hp + 64);  LDSC(h3, hp + 96);
      LDSC(h4, hp + 128);  LDSC(h5, hp + 160); LDSC(h6, hp + 192); LDSC(h7, hp + 224);
      LDSC(h8, hp + 256);  LDSC(h9, hp + 288); LDSC(ha, hp + 320); LDSC(hb2, hp + 352);
      LDSC(hc, hp + 384);  LDSC(hd, hp + 416); LDSC(he, hp + 448);
      vw15(h0, h1, h2, h3, h4, h5, h6, h7, h8, h9, ha, hb2, hc, hd, he);
      accA = MF(h0, wreg[0], accA);  accA = MF(h1, wreg[1], accA);
      accA = MF(h2, wreg[2], accA);  accA = MF(h3, wreg[3], accA);
      accA = MF(h4, wreg[4], accA);  accA = MF(h5, wreg[5], accA);
      accA = MF(h6, wreg[6], accA);  accA = MF(h7, wreg[7], accA);
      accA = MF(h8, wreg[8], accA);  accA = MF(h9, wreg[9], accA);
      accA = MF(ha, wreg[10], accA); accA = MF(hb2, wreg[11], accA);
      accA = MF(hc, wreg[12], accA); accA = MF(hd, wreg[13], accA);
      accA = MF(he, wreg[14], accA);
    } else {
      const unsigned short* hp = hb16_prev + (size_t)ab * NC + kg * 8 + 704;
      short8 h0, h1, h2, h3, h4, h5, h6, h7, h8, h9;
      LDSC(h0, hp);        LDSC(h1, hp + 32);  LDSC(h2, hp + 64);  LDSC(h3, hp + 96);
      LDSC(h4, hp + 128);  LDSC(h5, hp + 160); LDSC(h6, hp + 192); LDSC(h7, hp + 224);
      LDSC(h8, hp + 256);  LDSC(h9, hp + 288);
      short8 f0 = {0,0,0,0,0,0,0,0}, f1 = f0, f2 = f0, f3 = f0;
      if (j > 0) {
        const unsigned short* fp = F16 + ((size_t)(j - 1) * NB + ab) * 128 + kg * 8;
        f0 = *(const short8*)(fp);
        f1 = *(const short8*)(fp + 32);
        f2 = *(const short8*)(fp + 64);
        f3 = *(const short8*)(fp + 96);
      }
      vw10(h0, h1, h2, h3, h4, h5, h6, h7, h8, h9);
      accA = MF(h0, wreg[0], accA); accA = MF(h1, wreg[1], accA);
      accA = MF(h2, wreg[2], accA); accA = MF(h3, wreg[3], accA);
      accA = MF(h4, wreg[4], accA); accA = MF(h5, wreg[5], accA);
      accA = MF(h6, wreg[6], accA); accA = MF(h7, wreg[7], accA);
      accA = MF(h8, wreg[8], accA); accA = MF(h9, wreg[9], accA);
      accA = MF(f0, wreg[10], accA); accA = MF(f1, wreg[11], accA);
      accA = MF(f2, wreg[12], accA); accA = MF(f3, wreg[13], accA);
    }
    // Cred[m2][sg][r][lane]: sg 0=w0.A(q) 1=w0.B(h-part) 2=w1.A(prev) 3=w2.A 4=w3.A
    {
      auto cidx = [](int m, int sg, int r, int l) { return ((m * 5 + sg) * 4 + r) * 64 + l; };
      if (k4 == 0) {
#pragma unroll
        for (int r = 0; r < 4; ++r) {
          Cred[cidx(m2, 0, r, lane)] = accA[r];
          Cred[cidx(m2, 1, r, lane)] = accB[r];
        }
      } else {
        const int sg = 1 + k4;
#pragma unroll
        for (int r = 0; r < 4; ++r) Cred[cidx(m2, sg, r, lane)] = accA[r];
      }
    }
    __syncthreads();
    {  // combine: gate = s0 + swinv*s1 + s2  (n-gate keeps x/h split)
      const int n = tid & 15, b = tid >> 4;
      const int m2r = b >> 4, bm = b & 15, l = (bm >> 2) * 16 + n, r = bm & 3;
      auto cidx = [](int m, int sg, int rr, int ll) { return ((m * 5 + sg) * 4 + rr) * 64 + ll; };
      const float s0 = Cred[cidx(m2r, 0, r, l)];
      const float sB = Cred[cidx(m2r, 1, r, l)];
      const float s1 = Cred[cidx(m2r, 2, r, l)];
      const float s2 = sB + Cred[cidx(m2r, 3, r, l)] + Cred[cidx(m2r, 4, r, l)];
      const float swv = swinv_l[b];
      const int kind = n >> 2, c4o = n & 3;
      if (kind == 2) {
        gout2[2 * 128 + c4o * 32 + b] = s0 + swv * s1;
        gout2[3 * 128 + c4o * 32 + b] = s2;
      } else {
        const int slot = (kind == 3) ? 4 : kind;
        gout2[slot * 128 + c4o * 32 + b] = s0 + swv * s1 + s2;
      }
    }
    __syncthreads();
    if (tid < 128) {  // GRU update, 4 channels x 32 batches
      const int c4o = tid >> 5, b = tid & 31, c = cs + c4o;
      const float xr = gout2[0 * 128 + c4o * 32 + b] + b_ih[c] + b_hh[c];
      const float xz = gout2[1 * 128 + c4o * 32 + b] + b_ih[NC + c] + b_hh[NC + c];
      const float xn = gout2[2 * 128 + c4o * 32 + b] + b_ih[2 * NC + c];
      const float hn = gout2[3 * 128 + c4o * 32 + b] + b_hh[2 * NC + c];
      const float tp = gout2[4 * 128 + c4o * 32 + b];
      const float r = fsig(xr), z = fsig(xz);
      const float nn = ftanh(xn + r * hn);
      const float hnew = (1.f - z) * nn + z * h_prev[c * 32 + b];
      h_cur[c * 32 + b] = hnew;
      st_cg_u16(&hb16_cur[(size_t)b * NC + c], (unsigned short)f2bf(hnew));
      tredl[c4o * 32 + b] = w_t2[c] * ftanh(tp + b_t1[c]);
    }
    __syncthreads();
    if (tid < NB)
      st_cg(&TPART[bid * NB + tid],
            tredl[tid] + tredl[32 + tid] + tredl[64 + tid] + tredl[96 + tid]);
    gbarrier(root, flags, ph);

    // ========================== Phase Q ==========================
    if (bid < 32) {  // q = h_new @ w_q^T via MFMA; block owns 16 q-cols
      f32x4 qacc = {0.f, 0.f, 0.f, 0.f};
      const unsigned short* hb = HB16 + (size_t)p * NB * NC + (size_t)ab * NC + kg * 8;
      short8 g0, g1, g2, g3, g4, g5, g6, g7;
      LDSC(g0, hb + (k4 * 8 + 0) * 32); LDSC(g1, hb + (k4 * 8 + 1) * 32);
      LDSC(g2, hb + (k4 * 8 + 2) * 32); LDSC(g3, hb + (k4 * 8 + 3) * 32);
      LDSC(g4, hb + (k4 * 8 + 4) * 32); LDSC(g5, hb + (k4 * 8 + 5) * 32);
      LDSC(g6, hb + (k4 * 8 + 6) * 32); LDSC(g7, hb + (k4 * 8 + 7) * 32);
      const int col = lane & 15;
      const int jq = bid * 16 + col;
      const unsigned short* wp = WQ16 + (size_t)jq * NC + k4 * 8 * 32 + kg * 8;
      vw8(g0, g1, g2, g3, g4, g5, g6, g7);
      qacc = MF(g0, *(const short8*)(wp), qacc);
      qacc = MF(g1, *(const short8*)(wp + 32), qacc);
      qacc = MF(g2, *(const short8*)(wp + 64), qacc);
      qacc = MF(g3, *(const short8*)(wp + 96), qacc);
      qacc = MF(g4, *(const short8*)(wp + 128), qacc);
      qacc = MF(g5, *(const short8*)(wp + 160), qacc);
      qacc = MF(g6, *(const short8*)(wp + 192), qacc);
      qacc = MF(g7, *(const short8*)(wp + 224), qacc);
#pragma unroll
      for (int r = 0; r < 4; ++r) Cred[((m2 * 4 + k4) * 4 + r) * 64 + lane] = qacc[r];
      __syncthreads();
      {
        const int col2 = tid & 15, b2 = tid >> 4;
        const int m2r = b2 >> 4, bm = b2 & 15, l = (bm >> 2) * 16 + col2, r = bm & 3;
        float s = 0.f;
#pragma unroll
        for (int kk = 0; kk < 4; ++kk) s += Cred[((m2r * 4 + kk) * 4 + r) * 64 + l];
        st_cg(&QBUF[(size_t)b2 * NC2 + bid * 16 + col2], s);
      }
    } else if (bid >= 64 && bid < 96) {  // trans reduce for batch b = bid-64
      const int b2 = bid - 64;
      float v = (tid < NBLK) ? ld_cg(&TPART[tid * NB + b2]) : 0.f;
#pragma unroll
      for (int off = 32; off > 0; off >>= 1) v += __shfl_down(v, off);
      if (lane == 0) Cred[wv] = v;
      __syncthreads();
      if (tid == 0) {
        float s = 0.f;
#pragma unroll
        for (int w8 = 0; w8 < 8; ++w8) s += Cred[w8];
        st_cg(&TRED[b2], s);
      }
    }
    gbarrier(root, flags, ph);

    // ========================== Phase B ==========================
    {
      const int b = pb_b, s0 = pb_s0;
      if (tid == 0) {
        scal[0] = ld_cg(&se_prev[b]);
        scal[1] = ld_cg(&sw_prev[b]);
        scal[2] = ld_cg(&TRED[b]);
      }
      if (tid < 62) {  // raw e window (zero-padded conv halo); scale applied later
        const int sp = s0 + tid - 15;
        alignl[tid] = (sp >= 0 && sp < NS) ? ld_cg(&e_prev[b * NS + sp]) : 0.f;
      }
      if (tid >= 64 && tid < 97) {  // raw alpha_{j-1} halo for the shift term
        const int i2 = tid - 64, sp = s0 + i2 - 1;
        wl2[i2] = (sp >= 0 && sp < NS) ? ld_cg(&w_prev[b * NS + sp]) : 0.f;
      }
      const float qv = ld_cg(&QBUF[(size_t)b * NC2 + tid]);
      __syncthreads();
      const float invSE = 1.f / scal[0];
      const float invSW = 1.f / scal[1];
      const float tr = (j == 0) ? 0.5f : fsig(scal[2]);
      const int wvx = wv;
      float al[62];
#pragma unroll
      for (int x = 0; x < 62; ++x) al[x] = alignl[x];
      const unsigned* kp = (const unsigned*)&keyl[tid * KLSTRIDE];
#pragma unroll
      for (int sl8 = 0; sl8 < 4; ++sl8) {
#pragma unroll
        for (int i2 = 0; i2 < 4; ++i2) {
          const unsigned kw = kp[sl8 * 4 + i2];
#pragma unroll
          for (int hh = 0; hh < 2; ++hh) {
            const int sl = sl8 * 8 + i2 * 2 + hh;
            const float kv = bf2f((short)(hh ? (kw >> 16) : (kw & 0xffffu)));
            float conv = 0.f;
#pragma unroll
            for (int k = 0; k < 31; ++k) conv += wc[k] * al[sl + k];
            float pe = wag * ftanh(conv * invSE + qv + kv);
#pragma unroll
            for (int off = 32; off > 0; off >>= 1) pe += __shfl_down(pe, off);
            if (lane == 0) Epart[sl * 9 + wvx] = pe;
          }
        }
      }
      __syncthreads();
      if (tid < 32) {  // finalize energies for this block's 32 s-positions
        const int sl = tid, s = s0 + sl;
        float Ev = 0.f;
#pragma unroll
        for (int w8 = 0; w8 < 8; ++w8) Ev += Epart[sl * 9 + w8];
        const float ev = (mask[b * NS + s] != 0.f) ? __expf(Ev) : 0.f;
        const float csv = ((1.f - tr) * wl2[sl + 1] + tr * wl2[sl]) * invSW + 1e-7f;
        const float wvv = csv * ev;
        st_cg(&e_cur[b * NS + s], ev);
        st_cg(&w_cur[b * NS + s], wvv);
        wstash[sl] = wvv;
        float se = ev, sw2 = wvv;
#pragma unroll
        for (int off = 16; off > 0; off >>= 1) {
          se += __shfl_down(se, off, 32);
          sw2 += __shfl_down(sw2, off, 32);
        }
        if (sl == 0) { atomicAdd(&se_cur[b], se); atomicAdd(&sw_cur[b], sw2); }
      }
      __syncthreads();
      {  // prevU[b][i] += sum_s w_s * enc[b,s,i]
        float acc = 0.f;
        const float* encb = enc + ((size_t)(b * NS + s0)) * NI + tid;
#pragma unroll 8
        for (int ss = 0; ss < 32; ++ss) acc += wstash[ss] * encb[(size_t)ss * NI];
        atomicAdd(&pu_cur[(size_t)b * NI + tid], acc);
      }
    }
    gbarrier(root, flags, ph);
  }

  // epilogue: alpha_{T-1} (parity 1 since 799 is odd)
  if (bid < NB && tid < NS) {
    const float invSW = 1.f / ld_cg(&SWB[NB + bid]);
    out[((size_t)bid * NT + (NT - 1)) * NS + tid] =
        ld_cg(&WBUF[(size_t)NB * NS + bid * NS + tid]) * invSW;
  }
}

// ---------------------------------------------------------------------------
extern "C" void kernel_launch(void* const* d_in, const int* in_sizes, int n_in,
                              void* d_out, int out_size, void* d_ws, size_t ws_size,
                              hipStream_t stream) {
  const float* enc     = (const float*)d_in[0];
  const float* queries = (const float*)d_in[1];
  const float* outputs = (const float*)d_in[2];
  const float* mask    = (const float*)d_in[3];
  const float* w_ih    = (const float*)d_in[4];
  const float* w_hh    = (const float*)d_in[5];
  const float* b_ih    = (const float*)d_in[6];
  const float* b_hh    = (const float*)d_in[7];
  const float* w_q     = (const float*)d_in[8];
  const float* w_loc1  = (const float*)d_in[9];
  const float* w_loc2  = (const float*)d_in[10];
  const float* w_k     = (const float*)d_in[11];
  const float* b_k     = (const float*)d_in[12];
  const float* w_agg   = (const float*)d_in[13];
  const float* w_t1    = (const float*)d_in[14];
  const float* b_t1    = (const float*)d_in[15];
  const float* w_t2    = (const float*)d_in[16];
  float* ws = (float*)d_ws;
  float* out = (float*)d_out;
  (void)in_sizes; (void)n_in; (void)out_size; (void)ws_size;

  k_init<<<dim3(1024), dim3(256), 0, stream>>>(enc, queries, outputs, w_k, w_q, ws);
  k_key<<<dim3(NBLK), dim3(NTHR), 0, stream>>>(enc, b_k, ws);
  k_main<<<dim3(NBLK), dim3(NTHR), 0, stream>>>(enc, mask, w_ih, w_hh, b_ih, b_hh,
                                                w_loc1, w_loc2, w_agg, w_t1,
                                                b_t1, w_t2, ws, out);
}

// Round 6
// 21274.330 us; speedup vs baseline: 7.9652x; 1.2008x over previous
//
#include <hip/hip_runtime.h>
#include <cstdint>
#include <cstddef>

// ============================================================================
// Aligner (forward attention + GRU), persistent-kernel, MFMA-bf16 edition.
// Round 6: Phase-B energy computation moved to the matrix pipe.
//   conv(align) is a 512x32x32 matmul -> 8 MFMA/wave with the per-block
//   wcomb A-fragments persistent in VGPRs; qv+key enter as the MFMA
//   C-initializer (key slice persistent in 16 packed-bf16 VGPRs, constant
//   per block across all 800 steps). Kills the 992-FMA conv loop and the
//   192-shfl reduction storm that dominated VALUBusy in Round 5.
// Coherence model unchanged from Round 5 (no fences; sc0sc1 accesses + flag
// barrier).
// ============================================================================

namespace cfg {
constexpr int NB = 32, NS = 256, NI = 512, NHq = 256, NM = 80;
constexpr int NC = 1024, NC2 = 512, NT = 800;
constexpr int NBLK = 256, NTHR = 512;

constexpr size_t OFF_KEYT  = 0;                                   // 32*256*512 f32
constexpr size_t OFF_WKT   = OFF_KEYT + (size_t)NB * NS * NC2;    // 512*512 f32
constexpr size_t OFF_PU    = OFF_WKT + (size_t)NI * NC2;          // 2*32*512 f32 [b][i]
constexpr size_t OFF_H     = OFF_PU + (size_t)2 * NB * NI;        // 2*1024*32 f32 [c][b]
constexpr size_t OFF_H16   = OFF_H + (size_t)2 * NC * NB;         // 2*32*1024 u16 [b][c]
constexpr size_t OFF_E     = OFF_H16 + (size_t)NB * NC;           // 2*32*256 f32
constexpr size_t OFF_W     = OFF_E + (size_t)2 * NB * NS;         // 2*32*256 f32
constexpr size_t OFF_SE    = OFF_W + (size_t)2 * NB * NS;         // 64
constexpr size_t OFF_SW    = OFF_SE + 64;                         // 64
constexpr size_t OFF_TPART = OFF_SW + 64;                         // 256*32
constexpr size_t OFF_TRED  = OFF_TPART + (size_t)NBLK * NB;       // 32
constexpr size_t OFF_QBUF  = OFF_TRED + 32;                       // 32*512
constexpr size_t OFF_BAR   = OFF_QBUF + (size_t)NB * NC2;         // 4608 uints
constexpr size_t OFF_Q16   = OFF_BAR + 4608;                      // 800*32*256 u16
constexpr size_t OFF_F16   = OFF_Q16 + (size_t)NT * NB * NHq / 2; // 800*32*128 u16
constexpr size_t OFF_WQ16  = OFF_F16 + (size_t)NT * NB * 128 / 2; // 512*1024 u16
constexpr size_t WS_FLOATS = OFF_WQ16 + (size_t)NC2 * NC / 2;
}
using namespace cfg;

typedef __attribute__((ext_vector_type(8))) short short8;
typedef __attribute__((ext_vector_type(4))) float f32x4;

#define MF(a, b, c) __builtin_amdgcn_mfma_f32_16x16x32_bf16((a), (b), (c), 0, 0, 0)
// coherent (agent-scope, L1/L2-bypassing) 16B load, NO wait — group + vw*()
#define LDSC(d, p) asm volatile("global_load_dwordx4 %0, %1, off sc0 sc1" : "=v"(d) : "v"(p))

__device__ __forceinline__ float ld_cg(const float* p) {
  return __hip_atomic_load(p, __ATOMIC_RELAXED, __HIP_MEMORY_SCOPE_AGENT);
}
__device__ __forceinline__ void st_cg(float* p, float v) {
  __hip_atomic_store(p, v, __ATOMIC_RELAXED, __HIP_MEMORY_SCOPE_AGENT);
}
__device__ __forceinline__ void st_cg_u16(unsigned short* p, unsigned short v) {
  asm volatile("global_store_short %0, %1, off sc0 sc1" :: "v"(p), "v"((unsigned)v) : "memory");
}

__device__ __forceinline__ void vw7(short8& a0, short8& a1, short8& a2, short8& a3,
                                    short8& a4, short8& a5, short8& a6) {
  asm volatile("s_waitcnt vmcnt(0)"
               : "+v"(a0), "+v"(a1), "+v"(a2), "+v"(a3), "+v"(a4), "+v"(a5), "+v"(a6));
}
__device__ __forceinline__ void vw8(short8& a0, short8& a1, short8& a2, short8& a3,
                                    short8& a4, short8& a5, short8& a6, short8& a7) {
  asm volatile("s_waitcnt vmcnt(0)"
               : "+v"(a0), "+v"(a1), "+v"(a2), "+v"(a3), "+v"(a4), "+v"(a5), "+v"(a6), "+v"(a7));
}
__device__ __forceinline__ void vw10(short8& a0, short8& a1, short8& a2, short8& a3, short8& a4,
                                     short8& a5, short8& a6, short8& a7, short8& a8, short8& a9) {
  asm volatile("s_waitcnt vmcnt(0)"
               : "+v"(a0), "+v"(a1), "+v"(a2), "+v"(a3), "+v"(a4), "+v"(a5), "+v"(a6),
                 "+v"(a7), "+v"(a8), "+v"(a9));
}
__device__ __forceinline__ void vw15(short8& a0, short8& a1, short8& a2, short8& a3, short8& a4,
                                     short8& a5, short8& a6, short8& a7, short8& a8, short8& a9,
                                     short8& aa, short8& ab2, short8& ac, short8& ad, short8& ae) {
  asm volatile("s_waitcnt vmcnt(0)"
               : "+v"(a0), "+v"(a1), "+v"(a2), "+v"(a3), "+v"(a4), "+v"(a5), "+v"(a6),
                 "+v"(a7), "+v"(a8), "+v"(a9), "+v"(aa), "+v"(ab2), "+v"(ac), "+v"(ad), "+v"(ae));
}
__device__ __forceinline__ void vw16f(f32x4& a0, f32x4& a1, f32x4& a2, f32x4& a3, f32x4& a4,
                                      f32x4& a5, f32x4& a6, f32x4& a7, f32x4& b0, f32x4& b1,
                                      f32x4& b2, f32x4& b3, f32x4& b4, f32x4& b5, f32x4& b6,
                                      f32x4& b7) {
  asm volatile("s_waitcnt vmcnt(0)"
               : "+v"(a0), "+v"(a1), "+v"(a2), "+v"(a3), "+v"(a4), "+v"(a5), "+v"(a6), "+v"(a7),
                 "+v"(b0), "+v"(b1), "+v"(b2), "+v"(b3), "+v"(b4), "+v"(b5), "+v"(b6), "+v"(b7));
}

__device__ __forceinline__ float frcp(float x) {
#if __has_builtin(__builtin_amdgcn_rcpf)
  return __builtin_amdgcn_rcpf(x);
#else
  return 1.f / x;
#endif
}
__device__ __forceinline__ float fsig(float x) { return frcp(1.f + __expf(-x)); }
__device__ __forceinline__ float ftanh(float x) {
  const float e = __expf(2.f * x);
  return 1.f - 2.f * frcp(e + 1.f);
}
__device__ __forceinline__ short f2bf(float f) {  // RNE f32 -> bf16 bits
  unsigned u = __float_as_uint(f);
  u += 0x7FFFu + ((u >> 16) & 1u);
  return (short)(u >> 16);
}
__device__ __forceinline__ float bf2f(short s) {
  return __uint_as_float(((unsigned)(unsigned short)s) << 16);
}
__device__ __forceinline__ short8 cvt8(f32x4 lo, f32x4 hi) {
  short8 a;
  a[0] = f2bf(lo[0]); a[1] = f2bf(lo[1]); a[2] = f2bf(lo[2]); a[3] = f2bf(lo[3]);
  a[4] = f2bf(hi[0]); a[5] = f2bf(hi[1]); a[6] = f2bf(hi[2]); a[7] = f2bf(hi[3]);
  return a;
}

// Flag barrier (see Round 5 comments).
__device__ __forceinline__ void gbarrier(unsigned* root, unsigned* flags, unsigned& ph) {
  ++ph;
  asm volatile("s_waitcnt vmcnt(0)" ::: "memory");  // drain sc1 stores + atomics
  __syncthreads();
  if (blockIdx.x == 0) {
    const int t = threadIdx.x;
    if (t > 0 && t < 256) {
      while (__hip_atomic_load(&flags[t * 16], __ATOMIC_RELAXED, __HIP_MEMORY_SCOPE_AGENT) < ph)
        __builtin_amdgcn_s_sleep(1);
    }
    __syncthreads();
    if (t == 0)
      __hip_atomic_store(root, ph, __ATOMIC_RELAXED, __HIP_MEMORY_SCOPE_AGENT);
  } else {
    if (threadIdx.x == 0) {
      __hip_atomic_store(&flags[blockIdx.x * 16], ph, __ATOMIC_RELAXED, __HIP_MEMORY_SCOPE_AGENT);
      while (__hip_atomic_load(root, __ATOMIC_RELAXED, __HIP_MEMORY_SCOPE_AGENT) < ph)
        __builtin_amdgcn_s_sleep(1);
    }
  }
  __syncthreads();
}

// Wcat element (kind: 0=r,1=z,2=n,3=tp; c: channel; k: 0..1919)
__device__ __forceinline__ float wcat_val(const float* __restrict__ w_ih,
                                          const float* __restrict__ w_hh,
                                          const float* __restrict__ w_t1,
                                          int kind, int c, int k) {
  if (kind < 3) {
    const int gr = kind * NC + c;
    if (k < 768) return w_ih[(size_t)gr * 768 + k];
    if (k < 1792) return w_hh[(size_t)gr * NC + (k - 768)];
    return 0.f;
  }
  if (k >= 256 && k < 768) return w_t1[(size_t)c * 1616 + (k - 256)];
  if (k >= 768 && k < 1792) return w_t1[(size_t)c * 1616 + 592 + (k - 768)];
  if (k >= 1792 && k < 1872) return w_t1[(size_t)c * 1616 + 512 + (k - 1792)];
  return 0.f;
}

// ---------------------------------------------------------------------------
__global__ void k_init(const float* __restrict__ enc, const float* __restrict__ queries,
                       const float* __restrict__ outputs, const float* __restrict__ w_k,
                       const float* __restrict__ w_q, float* __restrict__ ws) {
  const size_t t0 = (size_t)blockIdx.x * blockDim.x + threadIdx.x;
  const size_t gs = (size_t)gridDim.x * blockDim.x;
  for (size_t x = t0; x < (size_t)NI * NC2; x += gs) {
    const int i = (int)(x / NC2), c2 = (int)(x % NC2);
    ws[OFF_WKT + x] = w_k[(size_t)c2 * NI + i];
  }
  // PU parity1 = enc[b,0,:]  (alpha_init one-hot at s=0, SW=1); parity0 = 0
  for (size_t x = t0; x < (size_t)NB * NI; x += gs) {
    const int b = (int)(x / NI), i = (int)(x % NI);
    ws[OFF_PU + x] = 0.f;
    ws[OFF_PU + (size_t)NB * NI + b * NI + i] = enc[(size_t)b * NS * NI + i];
  }
  for (size_t x = t0; x < (size_t)2 * NC * NB; x += gs) ws[OFF_H + x] = 0.f;
  for (size_t x = t0; x < (size_t)NB * NC; x += gs) ws[OFF_H16 + x] = 0.f;  // 2 u16 parities
  // e parity1 = 1 (SE=256); w parity1 = one-hot (SW=1)
  for (size_t x = t0; x < (size_t)NB * NS; x += gs) {
    ws[OFF_E + x] = 0.f;
    ws[OFF_E + (size_t)NB * NS + x] = 1.f;
    ws[OFF_W + x] = 0.f;
    ws[OFF_W + (size_t)NB * NS + x] = ((x & (NS - 1)) == 0) ? 1.f : 0.f;
  }
  for (size_t x = t0; x < (size_t)NB; x += gs) {
    ws[OFF_SE + x] = 0.f; ws[OFF_SE + NB + x] = (float)NS;
    ws[OFF_SW + x] = 0.f; ws[OFF_SW + NB + x] = 1.f;
    ws[OFF_TRED + x] = 0.f;
  }
  unsigned* bar = (unsigned*)(ws + OFF_BAR);
  for (size_t x = t0; x < 4608; x += gs) bar[x] = 0u;
  unsigned short* Q16 = (unsigned short*)(ws + OFF_Q16);
  for (size_t x = t0; x < (size_t)NT * NB * NHq; x += gs) {
    const int k = (int)(x & (NHq - 1));
    const int b = (int)((x >> 8) & (NB - 1));
    const int t = (int)(x >> 13);
    Q16[x] = (unsigned short)f2bf(queries[((size_t)b * NT + t) * NHq + k]);
  }
  unsigned short* F16 = (unsigned short*)(ws + OFF_F16);
  for (size_t x = t0; x < (size_t)NT * NB * 128; x += gs) {
    const int k = (int)(x & 127);
    const int b = (int)((x >> 7) & (NB - 1));
    const int t = (int)(x >> 12);
    F16[x] = (k < NM) ? (unsigned short)f2bf(outputs[((size_t)b * NT + t) * NM + k]) : 0;
  }
  unsigned short* WQ16 = (unsigned short*)(ws + OFF_WQ16);
  for (size_t x = t0; x < (size_t)NC2 * NC; x += gs)
    WQ16[x] = (unsigned short)f2bf(w_q[x]);
}

// ---------------------------------------------------------------------------
// keyT[b][s][c2] = enc[b,s,:] @ w_k^T + b_k
__global__ __launch_bounds__(NTHR) void k_key(const float* __restrict__ enc,
                                              const float* __restrict__ b_k,
                                              float* __restrict__ ws) {
  __shared__ float encl[4 * NI];
  const int bid = blockIdx.x, tid = threadIdx.x;
  const int b = bid >> 3, s0 = (bid & 7) * 32;
  const float* wkT = ws + OFF_WKT;
  float* keyT = ws + OFF_KEYT;
  const float bk = b_k[tid];
  for (int q = 0; q < 8; ++q) {
    const int sb = s0 + q * 4;
    for (int x = tid; x < 4 * NI; x += NTHR) {
      const int ss = x >> 9, i = x & (NI - 1);
      encl[x] = enc[((size_t)(b * NS + sb + ss)) * NI + i];
    }
    __syncthreads();
    float a0 = bk, a1 = bk, a2 = bk, a3 = bk;
    for (int i = 0; i < NI; ++i) {
      const float wv = wkT[(size_t)i * NC2 + tid];
      a0 += wv * encl[i];           a1 += wv * encl[NI + i];
      a2 += wv * encl[2 * NI + i];  a3 += wv * encl[3 * NI + i];
    }
    keyT[((size_t)(b * NS + sb + 0)) * NC2 + tid] = a0;
    keyT[((size_t)(b * NS + sb + 1)) * NC2 + tid] = a1;
    keyT[((size_t)(b * NS + sb + 2)) * NC2 + tid] = a2;
    keyT[((size_t)(b * NS + sb + 3)) * NC2 + tid] = a3;
    __syncthreads();
  }
}

// ---------------------------------------------------------------------------
__global__ __launch_bounds__(NTHR, 2) void k_main(
    const float* __restrict__ enc, const float* __restrict__ mask,
    const float* __restrict__ w_ih, const float* __restrict__ w_hh,
    const float* __restrict__ b_ih, const float* __restrict__ b_hh,
    const float* __restrict__ w_loc1, const float* __restrict__ w_loc2,
    const float* __restrict__ w_agg, const float* __restrict__ w_t1,
    const float* __restrict__ b_t1, const float* __restrict__ w_t2,
    float* ws, float* __restrict__ out) {
  const int bid = blockIdx.x, tid = threadIdx.x;
  float* const keyT = ws + OFF_KEYT;
  float* const PU = ws + OFF_PU;
  float* const HB = ws + OFF_H;
  unsigned short* const HB16 = (unsigned short*)(ws + OFF_H16);
  float* const EB = ws + OFF_E;
  float* const WBUF = ws + OFF_W;
  float* const SEB = ws + OFF_SE;
  float* const SWB = ws + OFF_SW;
  float* const TPART = ws + OFF_TPART;
  float* const TRED = ws + OFF_TRED;
  float* const QBUF = ws + OFF_QBUF;
  unsigned* const root = (unsigned*)(ws + OFF_BAR);
  unsigned* const flags = root + 16;
  const unsigned short* const Q16 = (const unsigned short*)(ws + OFF_Q16);
  const unsigned short* const F16 = (const unsigned short*)(ws + OFF_F16);
  const unsigned short* const WQ16 = (const unsigned short*)(ws + OFF_WQ16);

  __shared__ float Cred[2 * 5 * 4 * 64];           // MFMA cross-wave reduce
  __shared__ float gout2[5 * 4 * 32];              // r,z,nx,nh,tp per (c4,b)
  __shared__ float swinv_l[32];
  __shared__ float tredl[128];
  __shared__ float alignl[72];                     // raw e window; [62..71] = 0
  __shared__ float wl2[34];
  __shared__ float qbl[520];                       // staged q for this block's b
  __shared__ float Epart[32 * 9];
  __shared__ float wstash[32];
  __shared__ float scal[4];

  const int lane = tid & 63, wv = tid >> 6;
  const int m2 = wv >> 2, k4 = wv & 3;        // PA roles
  const int kg = lane >> 4;                   // A/B fragment k-group
  const int ab = m2 * 16 + (lane & 15);       // A batch index for this lane
  const int cs = bid * 4;                     // block's 4 GRU channels
  const int pb_b = bid >> 3, pb_s0 = (bid & 7) * 32;  // PB roles
  const int col = lane & 15, quad = lane >> 4;        // PB MFMA roles
  unsigned ph = 0;

  // ---- one-time staging -------------------------------------------------
  // B-fragments of Wcat, persistent in VGPRs: wreg[si] for this wave's steps.
  short8 wreg[16];
  {
    const int n = lane & 15;
    const int kind = n >> 2, ch = cs + (n & 3);
#pragma unroll
    for (int si = 0; si < 16; ++si) {
      int s = (k4 == 0) ? (si < 8 ? si : (si < 15 ? 16 + si : -1))
            : (k4 == 1) ? 8 + si
            : (k4 == 2) ? (si < 15 ? 31 + si : -1)
                        : (si < 14 ? 46 + si : -1);
      short8 w = {0, 0, 0, 0, 0, 0, 0, 0};
      if (s >= 0) {
        const int k0 = s * 32 + kg * 8;
#pragma unroll
        for (int jj = 0; jj < 8; ++jj)
          w[jj] = f2bf(wcat_val(w_ih, w_hh, w_t1, kind, ch, k0 + jj));
      }
      wreg[si] = w;
    }
  }
  // PB persistent fragments: wave wv owns c2-tiles 4wv..4wv+3 (m), both sl
  // tiles (n). A = wcomb[k][c2] (bf16), key slice packed bf16, wag f32.
  short8 wcA[4];
  unsigned keylo[4][2], keyhi[4][2];
  f32x4 wagr[4];
#pragma unroll
  for (int t = 0; t < 4; ++t) {
    const int mt = 4 * wv + t;
    short8 wfr;
#pragma unroll
    for (int jj = 0; jj < 8; ++jj) {
      const int k = quad * 8 + jj;
      float s = 0.f;
      if (k < 31) {
        const int c2 = mt * 16 + col;
        for (int l = 0; l < 32; ++l) s += w_loc2[c2 * 32 + l] * w_loc1[l * 31 + k];
      }
      wfr[jj] = f2bf(s);
    }
    wcA[t] = wfr;
    const int c2r = mt * 16 + quad * 4;
#pragma unroll
    for (int r = 0; r < 4; ++r) wagr[t][r] = w_agg[c2r + r];
#pragma unroll
    for (int nt = 0; nt < 2; ++nt) {
      const float* kp = &keyT[((size_t)(pb_b * NS + pb_s0 + nt * 16 + col)) * NC2 + c2r];
      keylo[t][nt] = ((unsigned)(unsigned short)f2bf(kp[0])) |
                     (((unsigned)(unsigned short)f2bf(kp[1])) << 16);
      keyhi[t][nt] = ((unsigned)(unsigned short)f2bf(kp[2])) |
                     (((unsigned)(unsigned short)f2bf(kp[3])) << 16);
    }
  }
  if (tid >= 62 && tid < 72) alignl[tid] = 0.f;  // conv zero-pad tail (k=31 col)
  __syncthreads();

  for (int j = 0; j < NT; ++j) {
    const int p = j & 1;
    const float* pu_prev = PU + (size_t)(1 - p) * NB * NI;
    float* pu_cur = PU + (size_t)p * NB * NI;
    const float* h_prev = HB + (size_t)(1 - p) * NC * NB;
    float* h_cur = HB + (size_t)p * NC * NB;
    const unsigned short* hb16_prev = HB16 + (size_t)(1 - p) * NB * NC;
    unsigned short* hb16_cur = HB16 + (size_t)p * NB * NC;
    const float* e_prev = EB + (size_t)(1 - p) * NB * NS;
    float* e_cur = EB + (size_t)p * NB * NS;
    const float* w_prev = WBUF + (size_t)(1 - p) * NB * NS;
    float* w_cur = WBUF + (size_t)p * NB * NS;
    const float* se_prev = SEB + (size_t)(1 - p) * NB;
    float* se_cur = SEB + (size_t)p * NB;
    const float* sw_prev = SWB + (size_t)(1 - p) * NB;
    float* sw_cur = SWB + (size_t)p * NB;

    // ========================== Phase A ==========================
    if (tid < 64) st_cg(&pu_cur[bid * 64 + tid], 0.f);
    if (bid == 0 && tid < NB) st_cg(&se_cur[tid], 0.f);
    if (bid == 1 && tid < NB) st_cg(&sw_cur[tid], 0.f);
    if (tid < NB) swinv_l[tid] = 1.f / ld_cg(&sw_prev[tid]);
    __syncthreads();

    if (j >= 1 && bid < NB && tid < NS)
      out[((size_t)bid * NT + (j - 1)) * NS + tid] = ld_cg(&w_prev[bid * NS + tid]) * swinv_l[bid];

    f32x4 accA = {0.f, 0.f, 0.f, 0.f}, accB = {0.f, 0.f, 0.f, 0.f};
    if (k4 == 0) {
      const unsigned short* qp = Q16 + ((size_t)j * NB + ab) * NHq + kg * 8;
      const unsigned short* hp = hb16_prev + (size_t)ab * NC + kg * 8;
      short8 h0, h1, h2, h3, h4, h5, h6;
      LDSC(h0, hp);        LDSC(h1, hp + 32);   LDSC(h2, hp + 64);  LDSC(h3, hp + 96);
      LDSC(h4, hp + 128);  LDSC(h5, hp + 160);  LDSC(h6, hp + 192);
      const short8 q0 = *(const short8*)(qp);
      const short8 q1 = *(const short8*)(qp + 32);
      const short8 q2 = *(const short8*)(qp + 64);
      const short8 q3 = *(const short8*)(qp + 96);
      const short8 q4 = *(const short8*)(qp + 128);
      const short8 q5 = *(const short8*)(qp + 160);
      const short8 q6 = *(const short8*)(qp + 192);
      const short8 q7 = *(const short8*)(qp + 224);
      vw7(h0, h1, h2, h3, h4, h5, h6);
      accA = MF(q0, wreg[0], accA); accA = MF(q1, wreg[1], accA);
      accA = MF(q2, wreg[2], accA); accA = MF(q3, wreg[3], accA);
      accA = MF(q4, wreg[4], accA); accA = MF(q5, wreg[5], accA);
      accA = MF(q6, wreg[6], accA); accA = MF(q7, wreg[7], accA);
      accB = MF(h0, wreg[8], accB);  accB = MF(h1, wreg[9], accB);
      accB = MF(h2, wreg[10], accB); accB = MF(h3, wreg[11], accB);
      accB = MF(h4, wreg[12], accB); accB = MF(h5, wreg[13], accB);
      accB = MF(h6, wreg[14], accB);
    } else if (k4 == 1) {
      const float* pp = pu_prev + (size_t)ab * NI + kg * 8;
#pragma unroll
      for (int rd = 0; rd < 2; ++rd) {
        const float* pb = pp + rd * 256;
        f32x4 a0, a1, a2, a3, a4, a5, a6, a7, b0, b1, b2, b3, b4, b5, b6, b7;
        LDSC(a0, pb);        LDSC(b0, pb + 4);
        LDSC(a1, pb + 32);   LDSC(b1, pb + 36);
        LDSC(a2, pb + 64);   LDSC(b2, pb + 68);
        LDSC(a3, pb + 96);   LDSC(b3, pb + 100);
        LDSC(a4, pb + 128);  LDSC(b4, pb + 132);
        LDSC(a5, pb + 160);  LDSC(b5, pb + 164);
        LDSC(a6, pb + 192);  LDSC(b6, pb + 196);
        LDSC(a7, pb + 224);  LDSC(b7, pb + 228);
        vw16f(a0, a1, a2, a3, a4, a5, a6, a7, b0, b1, b2, b3, b4, b5, b6, b7);
        const int w0 = rd * 8;
        accA = MF(cvt8(a0, b0), wreg[w0 + 0], accA);
        accA = MF(cvt8(a1, b1), wreg[w0 + 1], accA);
        accA = MF(cvt8(a2, b2), wreg[w0 + 2], accA);
        accA = MF(cvt8(a3, b3), wreg[w0 + 3], accA);
        accA = MF(cvt8(a4, b4), wreg[w0 + 4], accA);
        accA = MF(cvt8(a5, b5), wreg[w0 + 5], accA);
        accA = MF(cvt8(a6, b6), wreg[w0 + 6], accA);
        accA = MF(cvt8(a7, b7), wreg[w0 + 7], accA);
      }
    } else if (k4 == 2) {
      const unsigned short* hp = hb16_prev + (size_t)ab * NC + kg * 8 + 224;
      short8 h0, h1, h2, h3, h4, h5, h6, h7, h8, h9, ha, hb2, hc, hd, he;
      LDSC(h0, hp);        LDSC(h1, hp + 32);  LDSC(h2, hp + 64);  LDSC(h3, hp + 96);
      LDSC(h4, hp + 128);  LDSC(h5, hp + 160); LDSC(h6, hp + 192); LDSC(h7, hp + 224);
      LDSC(h8, hp + 256);  LDSC(h9, hp + 288); LDSC(ha, hp + 320); LDSC(hb2, hp + 352);
      LDSC(hc, hp + 384);  LDSC(hd, hp + 416); LDSC(he, hp + 448);
      vw15(h0, h1, h2, h3, h4, h5, h6, h7, h8, h9, ha, hb2, hc, hd, he);
      accA = MF(h0, wreg[0], accA);  accA = MF(h1, wreg[1], accA);
      accA = MF(h2, wreg[2], accA);  accA = MF(h3, wreg[3], accA);
      accA = MF(h4, wreg[4], accA);  accA = MF(h5, wreg[5], accA);
      accA = MF(h6, wreg[6], accA);  accA = MF(h7, wreg[7], accA);
      accA = MF(h8, wreg[8], accA);  accA = MF(h9, wreg[9], accA);
      accA = MF(ha, wreg[10], accA); accA = MF(hb2, wreg[11], accA);
      accA = MF(hc, wreg[12], accA); accA = MF(hd, wreg[13], accA);
      accA = MF(he, wreg[14], accA);
    } else {
      const unsigned short* hp = hb16_prev + (size_t)ab * NC + kg * 8 + 704;
      short8 h0, h1, h2, h3, h4, h5, h6, h7, h8, h9;
      LDSC(h0, hp);        LDSC(h1, hp + 32);  LDSC(h2, hp + 64);  LDSC(h3, hp + 96);
      LDSC(h4, hp + 128);  LDSC(h5, hp + 160); LDSC(h6, hp + 192); LDSC(h7, hp + 224);
      LDSC(h8, hp + 256);  LDSC(h9, hp + 288);
      short8 f0 = {0,0,0,0,0,0,0,0}, f1 = f0, f2 = f0, f3 = f0;
      if (j > 0) {
        const unsigned short* fp = F16 + ((size_t)(j - 1) * NB + ab) * 128 + kg * 8;
        f0 = *(const short8*)(fp);
        f1 = *(const short8*)(fp + 32);
        f2 = *(const short8*)(fp + 64);
        f3 = *(const short8*)(fp + 96);
      }
      vw10(h0, h1, h2, h3, h4, h5, h6, h7, h8, h9);
      accA = MF(h0, wreg[0], accA); accA = MF(h1, wreg[1], accA);
      accA = MF(h2, wreg[2], accA); accA = MF(h3, wreg[3], accA);
      accA = MF(h4, wreg[4], accA); accA = MF(h5, wreg[5], accA);
      accA = MF(h6, wreg[6], accA); accA = MF(h7, wreg[7], accA);
      accA = MF(h8, wreg[8], accA); accA = MF(h9, wreg[9], accA);
      accA = MF(f0, wreg[10], accA); accA = MF(f1, wreg[11], accA);
      accA = MF(f2, wreg[12], accA); accA = MF(f3, wreg[13], accA);
    }
    // Cred[m2][sg][r][lane]: sg 0=w0.A(q) 1=w0.B(h-part) 2=w1.A(prev) 3=w2.A 4=w3.A
    {
      auto cidx = [](int m, int sg, int r, int l) { return ((m * 5 + sg) * 4 + r) * 64 + l; };
      if (k4 == 0) {
#pragma unroll
        for (int r = 0; r < 4; ++r) {
          Cred[cidx(m2, 0, r, lane)] = accA[r];
          Cred[cidx(m2, 1, r, lane)] = accB[r];
        }
      } else {
        const int sg = 1 + k4;
#pragma unroll
        for (int r = 0; r < 4; ++r) Cred[cidx(m2, sg, r, lane)] = accA[r];
      }
    }
    __syncthreads();
    {  // combine: gate = s0 + swinv*s1 + s2  (n-gate keeps x/h split)
      const int n = tid & 15, b = tid >> 4;
      const int m2r = b >> 4, bm = b & 15, l = (bm >> 2) * 16 + n, r = bm & 3;
      auto cidx = [](int m, int sg, int rr, int ll) { return ((m * 5 + sg) * 4 + rr) * 64 + ll; };
      const float s0 = Cred[cidx(m2r, 0, r, l)];
      const float sB = Cred[cidx(m2r, 1, r, l)];
      const float s1 = Cred[cidx(m2r, 2, r, l)];
      const float s2 = sB + Cred[cidx(m2r, 3, r, l)] + Cred[cidx(m2r, 4, r, l)];
      const float swv = swinv_l[b];
      const int kind = n >> 2, c4o = n & 3;
      if (kind == 2) {
        gout2[2 * 128 + c4o * 32 + b] = s0 + swv * s1;
        gout2[3 * 128 + c4o * 32 + b] = s2;
      } else {
        const int slot = (kind == 3) ? 4 : kind;
        gout2[slot * 128 + c4o * 32 + b] = s0 + swv * s1 + s2;
      }
    }
    __syncthreads();
    if (tid < 128) {  // GRU update, 4 channels x 32 batches
      const int c4o = tid >> 5, b = tid & 31, c = cs + c4o;
      const float xr = gout2[0 * 128 + c4o * 32 + b] + b_ih[c] + b_hh[c];
      const float xz = gout2[1 * 128 + c4o * 32 + b] + b_ih[NC + c] + b_hh[NC + c];
      const float xn = gout2[2 * 128 + c4o * 32 + b] + b_ih[2 * NC + c];
      const float hn = gout2[3 * 128 + c4o * 32 + b] + b_hh[2 * NC + c];
      const float tp = gout2[4 * 128 + c4o * 32 + b];
      const float r = fsig(xr), z = fsig(xz);
      const float nn = ftanh(xn + r * hn);
      const float hnew = (1.f - z) * nn + z * h_prev[c * 32 + b];
      h_cur[c * 32 + b] = hnew;
      st_cg_u16(&hb16_cur[(size_t)b * NC + c], (unsigned short)f2bf(hnew));
      tredl[c4o * 32 + b] = w_t2[c] * ftanh(tp + b_t1[c]);
    }
    __syncthreads();
    if (tid < NB)
      st_cg(&TPART[bid * NB + tid],
            tredl[tid] + tredl[32 + tid] + tredl[64 + tid] + tredl[96 + tid]);
    gbarrier(root, flags, ph);

    // ========================== Phase Q ==========================
    if (bid < 32) {  // q = h_new @ w_q^T via MFMA; block owns 16 q-cols
      f32x4 qacc = {0.f, 0.f, 0.f, 0.f};
      const unsigned short* hb = HB16 + (size_t)p * NB * NC + (size_t)ab * NC + kg * 8;
      short8 g0, g1, g2, g3, g4, g5, g6, g7;
      LDSC(g0, hb + (k4 * 8 + 0) * 32); LDSC(g1, hb + (k4 * 8 + 1) * 32);
      LDSC(g2, hb + (k4 * 8 + 2) * 32); LDSC(g3, hb + (k4 * 8 + 3) * 32);
      LDSC(g4, hb + (k4 * 8 + 4) * 32); LDSC(g5, hb + (k4 * 8 + 5) * 32);
      LDSC(g6, hb + (k4 * 8 + 6) * 32); LDSC(g7, hb + (k4 * 8 + 7) * 32);
      const int jq = bid * 16 + col;
      const unsigned short* wp = WQ16 + (size_t)jq * NC + k4 * 8 * 32 + kg * 8;
      vw8(g0, g1, g2, g3, g4, g5, g6, g7);
      qacc = MF(g0, *(const short8*)(wp), qacc);
      qacc = MF(g1, *(const short8*)(wp + 32), qacc);
      qacc = MF(g2, *(const short8*)(wp + 64), qacc);
      qacc = MF(g3, *(const short8*)(wp + 96), qacc);
      qacc = MF(g4, *(const short8*)(wp + 128), qacc);
      qacc = MF(g5, *(const short8*)(wp + 160), qacc);
      qacc = MF(g6, *(const short8*)(wp + 192), qacc);
      qacc = MF(g7, *(const short8*)(wp + 224), qacc);
#pragma unroll
      for (int r = 0; r < 4; ++r) Cred[((m2 * 4 + k4) * 4 + r) * 64 + lane] = qacc[r];
      __syncthreads();
      {
        const int col2 = tid & 15, b2 = tid >> 4;
        const int m2r = b2 >> 4, bm = b2 & 15, l = (bm >> 2) * 16 + col2, r = bm & 3;
        float s = 0.f;
#pragma unroll
        for (int kk = 0; kk < 4; ++kk) s += Cred[((m2r * 4 + kk) * 4 + r) * 64 + l];
        st_cg(&QBUF[(size_t)b2 * NC2 + bid * 16 + col2], s);
      }
    } else if (bid >= 64 && bid < 96) {  // trans reduce for batch b = bid-64
      const int b2 = bid - 64;
      float v = (tid < NBLK) ? ld_cg(&TPART[tid * NB + b2]) : 0.f;
#pragma unroll
      for (int off = 32; off > 0; off >>= 1) v += __shfl_down(v, off);
      if (lane == 0) Cred[wv] = v;
      __syncthreads();
      if (tid == 0) {
        float s = 0.f;
#pragma unroll
        for (int w8 = 0; w8 < 8; ++w8) s += Cred[w8];
        st_cg(&TRED[b2], s);
      }
    }
    gbarrier(root, flags, ph);

    // ========================== Phase B ==========================
    {
      const int b = pb_b, s0v = pb_s0;
      if (tid == 0) {
        scal[0] = ld_cg(&se_prev[b]);
        scal[1] = ld_cg(&sw_prev[b]);
        scal[2] = ld_cg(&TRED[b]);
      }
      qbl[tid] = ld_cg(&QBUF[(size_t)b * NC2 + tid]);  // stage q -> LDS
      if (tid < 62) {  // raw e window (zero-padded conv halo)
        const int sp = s0v + tid - 15;
        alignl[tid] = (sp >= 0 && sp < NS) ? ld_cg(&e_prev[b * NS + sp]) : 0.f;
      }
      if (tid >= 64 && tid < 97) {  // raw alpha_{j-1} halo for the shift term
        const int i2 = tid - 64, sp = s0v + i2 - 1;
        wl2[i2] = (sp >= 0 && sp < NS) ? ld_cg(&w_prev[b * NS + sp]) : 0.f;
      }
      __syncthreads();
      const float invSE = 1.f / scal[0];
      const float invSW = 1.f / scal[1];
      const float tr = (j == 0) ? 0.5f : fsig(scal[2]);
      // B-frags: align window in MFMA B layout (k=quad*8+j, n=sl=nt*16+col)
      short8 bfr[2];
#pragma unroll
      for (int nt = 0; nt < 2; ++nt) {
        const int base = nt * 16 + col + quad * 8;
        short8 bv;
#pragma unroll
        for (int jj = 0; jj < 8; ++jj) bv[jj] = f2bf(alignl[base + jj] * invSE);
        bfr[nt] = bv;
      }
      // 8 MFMA: D[c2][sl] = wcomb·align + (q + key); epilogue tanh·wag + reduce
#pragma unroll
      for (int nt = 0; nt < 2; ++nt) {
        float pe = 0.f;
#pragma unroll
        for (int t = 0; t < 4; ++t) {
          const int c2b = (4 * wv + t) * 16 + quad * 4;
          f32x4 acc;
          acc[0] = qbl[c2b + 0] + __uint_as_float(keylo[t][nt] << 16);
          acc[1] = qbl[c2b + 1] + __uint_as_float(keylo[t][nt] & 0xffff0000u);
          acc[2] = qbl[c2b + 2] + __uint_as_float(keyhi[t][nt] << 16);
          acc[3] = qbl[c2b + 3] + __uint_as_float(keyhi[t][nt] & 0xffff0000u);
          acc = MF(wcA[t], bfr[nt], acc);
          pe += wagr[t][0] * ftanh(acc[0]);
          pe += wagr[t][1] * ftanh(acc[1]);
          pe += wagr[t][2] * ftanh(acc[2]);
          pe += wagr[t][3] * ftanh(acc[3]);
        }
        pe += __shfl_xor(pe, 16);
        pe += __shfl_xor(pe, 32);
        if (lane < 16) Epart[(nt * 16 + col) * 9 + wv] = pe;
      }
      __syncthreads();
      if (tid < 32) {  // finalize energies for this block's 32 s-positions
        const int sl = tid, s = s0v + sl;
        float Ev = 0.f;
#pragma unroll
        for (int w8 = 0; w8 < 8; ++w8) Ev += Epart[sl * 9 + w8];
        const float ev = (mask[b * NS + s] != 0.f) ? __expf(Ev) : 0.f;
        const float csv = ((1.f - tr) * wl2[sl + 1] + tr * wl2[sl]) * invSW + 1e-7f;
        const float wvv = csv * ev;
        st_cg(&e_cur[b * NS + s], ev);
        st_cg(&w_cur[b * NS + s], wvv);
        wstash[sl] = wvv;
        float se = ev, sw2 = wvv;
#pragma unroll
        for (int off = 16; off > 0; off >>= 1) {
          se += __shfl_down(se, off, 32);
          sw2 += __shfl_down(sw2, off, 32);
        }
        if (sl == 0) { atomicAdd(&se_cur[b], se); atomicAdd(&sw_cur[b], sw2); }
      }
      __syncthreads();
      {  // prevU[b][i] += sum_s w_s * enc[b,s,i]
        float acc = 0.f;
        const float* encb = enc + ((size_t)(b * NS + s0v)) * NI + tid;
#pragma unroll 8
        for (int ss = 0; ss < 32; ++ss) acc += wstash[ss] * encb[(size_t)ss * NI];
        atomicAdd(&pu_cur[(size_t)b * NI + tid], acc);
      }
    }
    gbarrier(root, flags, ph);
  }

  // epilogue: alpha_{T-1} (parity 1 since 799 is odd)
  if (bid < NB && tid < NS) {
    const float invSW = 1.f / ld_cg(&SWB[NB + bid]);
    out[((size_t)bid * NT + (NT - 1)) * NS + tid] =
        ld_cg(&WBUF[(size_t)NB * NS + bid * NS + tid]) * invSW;
  }
}

// ---------------------------------------------------------------------------
extern "C" void kernel_launch(void* const* d_in, const int* in_sizes, int n_in,
                              void* d_out, int out_size, void* d_ws, size_t ws_size,
                              hipStream_t stream) {
  const float* enc     = (const float*)d_in[0];
  const float* queries = (const float*)d_in[1];
  const float* outputs = (const float*)d_in[2];
  const float* mask    = (const float*)d_in[3];
  const float* w_ih    = (const float*)d_in[4];
  const float* w_hh    = (const float*)d_in[5];
  const float* b_ih    = (const float*)d_in[6];
  const float* b_hh    = (const float*)d_in[7];
  const float* w_q     = (const float*)d_in[8];
  const float* w_loc1  = (const float*)d_in[9];
  const float* w_loc2  = (const float*)d_in[10];
  const float* w_k     = (const float*)d_in[11];
  const float* b_k     = (const float*)d_in[12];
  const float* w_agg   = (const float*)d_in[13];
  const float* w_t1    = (const float*)d_in[14];
  const float* b_t1    = (const float*)d_in[15];
  const float* w_t2    = (const float*)d_in[16];
  float* ws = (float*)d_ws;
  float* out = (float*)d_out;
  (void)in_sizes; (void)n_in; (void)out_size; (void)ws_size;

  k_init<<<dim3(1024), dim3(256), 0, stream>>>(enc, queries, outputs, w_k, w_q, ws);
  k_key<<<dim3(NBLK), dim3(NTHR), 0, stream>>>(enc, b_k, ws);
  k_main<<<dim3(NBLK), dim3(NTHR), 0, stream>>>(enc, mask, w_ih, w_hh, b_ih, b_hh,
                                                w_loc1, w_loc2, w_agg, w_t1,
                                                b_t1, w_t2, ws, out);
}